// Round 11
// baseline (2262.472 us; speedup 1.0000x reference)
//
#include <hip/hip_runtime.h>
#include <cstdint>

#define NB    64
#define LIMG  196
#define DIMG  2048
#define RNND  1024
#define EMBD  512
#define TSTEPS 17
#define VOUTD 10003

typedef short bf16x8 __attribute__((ext_vector_type(8)));
typedef float f32x4  __attribute__((ext_vector_type(4)));

__device__ __forceinline__ float fast_sig(float x) {
    return 1.f / (1.f + __expf(-x));
}
__device__ __forceinline__ float fast_tanh(float x) {
    float ax = fabsf(x);
    float e  = __expf(2.f * ax);
    float r  = 1.f - 2.f / (e + 1.f);
    return copysignf(r, x);
}
__device__ __forceinline__ void split_bf(float x, short& hi, short& lo) {
    unsigned u  = __float_as_uint(x);
    unsigned hb = u & 0xffff0000u;
    hi = (short)(u >> 16);
    float r = x - __uint_as_float(hb);
    lo = (short)(__float_as_uint(r) >> 16);
}

// ---------------------------------------------------------------------------
// Transpose + bf16 hi/lo split of weights
// ---------------------------------------------------------------------------
__global__ __launch_bounds__(256) void tsplit(
    const float* __restrict__ S1, int ld1,
    const float* __restrict__ S2, int ld2,
    short* __restrict__ outh, short* __restrict__ outl,
    int N, int K, int ksplit, int nsplit)
{
    __shared__ float T[64][65];
    const int k0 = blockIdx.x * 64, n0 = blockIdx.y * 64;
    const int tid = threadIdx.x;
    const int rr = tid >> 2;
    const int cc = (tid & 3) * 16;
    const int kk = k0 + rr;
    const int nn = n0 + cc;
    const float* rp; int col;
    if (nsplit > 0) {
        if (nn >= nsplit) { rp = S2 + (size_t)kk * ld2; col = nn - nsplit; }
        else              { rp = S1 + (size_t)kk * ld1; col = nn; }
    } else {
        if (kk < ksplit)  { rp = S1 + (size_t)kk * ld1; col = nn; }
        else              { rp = S2 + (size_t)(kk - ksplit) * ld2; col = nn; }
    }
#pragma unroll
    for (int j = 0; j < 16; j++)
        T[rr][cc + j] = (nn + j < N) ? rp[col + j] : 0.f;
    __syncthreads();
    const int wn = tid >> 2;
    const int wk = (tid & 3) * 16;
    const int gn = n0 + wn;
    if (gn >= N) return;
    bf16x8 h0, h1, l0, l1;
#pragma unroll
    for (int j = 0; j < 8; j++) {
        short hh, ll;
        split_bf(T[wk + j][wn], hh, ll);     h0[j] = hh; l0[j] = ll;
        split_bf(T[wk + 8 + j][wn], hh, ll); h1[j] = hh; l1[j] = ll;
    }
    const size_t o = (size_t)gn * K + k0 + wk;
    *(bf16x8*)&outh[o]     = h0;
    *(bf16x8*)&outh[o + 8] = h1;
    *(bf16x8*)&outl[o]     = l0;
    *(bf16x8*)&outl[o + 8] = l1;
}

// ---------------------------------------------------------------------------
// m-tiled 64x128 bf16x3 MFMA GEMM (R9 config: plain 2-D grid, no hints).
// grid (N/128 ceil, M/64). A: f32 (Af) split on the fly, or bf16 pair.
// B pre-split [N][K] bf16 pair. Direct epilogue: bias + optional pmap
// (row -> (row&63)*17 + (row>>6)). Register prefetch of next K-tile.
// ---------------------------------------------------------------------------
__global__ __launch_bounds__(256) void gemm_mt(
    const float* __restrict__ Af,
    const short* __restrict__ Ah16, const short* __restrict__ Al16,
    const short* __restrict__ Bh16, const short* __restrict__ Bl16,
    const float* __restrict__ bias, float* __restrict__ C,
    int N, int K, int lda, int ldb, int ldc, int pmap)
{
    __shared__ short Ah[64 * 40], Al[64 * 40];
    __shared__ short Bh[128 * 40], Bl[128 * 40];

    const int tid = threadIdx.x;
    const int n0  = blockIdx.x * 128;
    const int m0  = blockIdx.y * 64;

    const int lane = tid & 63;
    const int w    = tid >> 6;
    const int wn   = w * 32;
    const int lm   = lane & 15;
    const int lk   = lane >> 4;

    const int a_r = tid >> 2;
    const int a_c = (tid & 3) * 8;
    const int b_r = tid >> 1;
    const int b_c = (tid & 1) * 16;

    f32x4 acc[4][2];
#pragma unroll
    for (int i = 0; i < 4; i++)
#pragma unroll
        for (int j = 0; j < 2; j++) acc[i][j] = (f32x4)0.f;

    bf16x8 rah, ral, rbh0, rbh1, rbl0, rbl1;
    auto load_tile = [&](int k0) {
        if (Af) {
            const float* ap = Af + (size_t)(m0 + a_r) * lda + (k0 + a_c);
            float4 q0 = *(const float4*)(ap);
            float4 q1 = *(const float4*)(ap + 4);
            float f[8] = {q0.x, q0.y, q0.z, q0.w, q1.x, q1.y, q1.z, q1.w};
#pragma unroll
            for (int j = 0; j < 8; j++) {
                short hh, ll;
                split_bf(f[j], hh, ll); rah[j] = hh; ral[j] = ll;
            }
        } else {
            rah = *(const bf16x8*)(Ah16 + (size_t)(m0 + a_r) * lda + (k0 + a_c));
            ral = *(const bf16x8*)(Al16 + (size_t)(m0 + a_r) * lda + (k0 + a_c));
        }
        const short* pb = Bh16 + (size_t)(n0 + b_r) * ldb + (k0 + b_c);
        rbh0 = *(const bf16x8*)pb; rbh1 = *(const bf16x8*)(pb + 8);
        const short* qb = Bl16 + (size_t)(n0 + b_r) * ldb + (k0 + b_c);
        rbl0 = *(const bf16x8*)qb; rbl1 = *(const bf16x8*)(qb + 8);
    };

    load_tile(0);
    for (int k0 = 0; k0 < K; k0 += 32) {
        __syncthreads();
        *(bf16x8*)&Ah[a_r * 40 + a_c] = rah;
        *(bf16x8*)&Al[a_r * 40 + a_c] = ral;
        *(bf16x8*)&Bh[b_r * 40 + b_c]     = rbh0;
        *(bf16x8*)&Bh[b_r * 40 + b_c + 8] = rbh1;
        *(bf16x8*)&Bl[b_r * 40 + b_c]     = rbl0;
        *(bf16x8*)&Bl[b_r * 40 + b_c + 8] = rbl1;
        __syncthreads();
        if (k0 + 32 < K) load_tile(k0 + 32);   // prefetch hides under MFMAs

        bf16x8 afh[4], afl[4], bfh[2], bfl[2];
#pragma unroll
        for (int fm = 0; fm < 4; fm++) {
            const int idx = (fm * 16 + lm) * 40 + lk * 8;
            afh[fm] = *(bf16x8*)&Ah[idx];
            afl[fm] = *(bf16x8*)&Al[idx];
        }
#pragma unroll
        for (int fn = 0; fn < 2; fn++) {
            const int idx = (wn + fn * 16 + lm) * 40 + lk * 8;
            bfh[fn] = *(bf16x8*)&Bh[idx];
            bfl[fn] = *(bf16x8*)&Bl[idx];
        }
#pragma unroll
        for (int fm = 0; fm < 4; fm++)
#pragma unroll
            for (int fn = 0; fn < 2; fn++) {
                acc[fm][fn] = __builtin_amdgcn_mfma_f32_16x16x32_bf16(afh[fm], bfh[fn], acc[fm][fn], 0, 0, 0);
                acc[fm][fn] = __builtin_amdgcn_mfma_f32_16x16x32_bf16(afh[fm], bfl[fn], acc[fm][fn], 0, 0, 0);
                acc[fm][fn] = __builtin_amdgcn_mfma_f32_16x16x32_bf16(afl[fm], bfh[fn], acc[fm][fn], 0, 0, 0);
            }
    }

#pragma unroll
    for (int fm = 0; fm < 4; fm++)
#pragma unroll
        for (int fn = 0; fn < 2; fn++) {
            const int col = n0 + wn + fn * 16 + lm;
            if (col >= N) continue;
            const float bb = bias ? bias[col] : 0.f;
#pragma unroll
            for (int r = 0; r < 4; r++) {
                const int row = m0 + fm * 16 + lk * 4 + r;
                const size_t orow = pmap ? (size_t)((row & 63) * TSTEPS + (row >> 6))
                                         : (size_t)row;
                C[orow * ldc + col] = acc[fm][fn][r] + bb;
            }
        }
}

// ---------------------------------------------------------------------------
// Skinny bf16x3 MFMA GEMM, split-K partials (round-6 version).
// ---------------------------------------------------------------------------
__global__ __launch_bounds__(256) void gemm_sk(
    const float* __restrict__ A,
    const short* __restrict__ Bh16, const short* __restrict__ Bl16,
    float* __restrict__ P, int N, int K, int lda, int ldb, int Kc)
{
    __shared__ short Ah[64 * 40], Al[64 * 40];
    __shared__ short Bh[128 * 40], Bl[128 * 40];

    const int tid = threadIdx.x;
    const int n0  = blockIdx.x * 128;
    const int s   = blockIdx.z;
    const int kb  = s * Kc;

    const int lane = tid & 63;
    const int w    = tid >> 6;
    const int wn   = w * 32;
    const int lm   = lane & 15;
    const int lk   = lane >> 4;

    const int a_r = tid >> 2;
    const int a_c = (tid & 3) * 8;
    const int b_r = tid >> 1;
    const int b_c = (tid & 1) * 16;

    f32x4 acc[4][2];
#pragma unroll
    for (int i = 0; i < 4; i++)
#pragma unroll
        for (int j = 0; j < 2; j++) acc[i][j] = (f32x4)0.f;

    for (int k0 = kb; k0 < kb + Kc; k0 += 32) {
        const float* ap = A + (size_t)a_r * lda + (k0 + a_c);
        float4 q0 = *(const float4*)(ap);
        float4 q1 = *(const float4*)(ap + 4);
        float f[8] = {q0.x, q0.y, q0.z, q0.w, q1.x, q1.y, q1.z, q1.w};
        bf16x8 ah, al;
#pragma unroll
        for (int j = 0; j < 8; j++) {
            short hh, ll;
            split_bf(f[j], hh, ll); ah[j] = hh; al[j] = ll;
        }
        const short* pb = Bh16 + (size_t)(n0 + b_r) * ldb + (k0 + b_c);
        bf16x8 bh0 = *(const bf16x8*)pb, bh1 = *(const bf16x8*)(pb + 8);
        const short* qb = Bl16 + (size_t)(n0 + b_r) * ldb + (k0 + b_c);
        bf16x8 bl0 = *(const bf16x8*)qb, bl1 = *(const bf16x8*)(qb + 8);

        __syncthreads();
        *(bf16x8*)&Ah[a_r * 40 + a_c] = ah;
        *(bf16x8*)&Al[a_r * 40 + a_c] = al;
        *(bf16x8*)&Bh[b_r * 40 + b_c]     = bh0;
        *(bf16x8*)&Bh[b_r * 40 + b_c + 8] = bh1;
        *(bf16x8*)&Bl[b_r * 40 + b_c]     = bl0;
        *(bf16x8*)&Bl[b_r * 40 + b_c + 8] = bl1;
        __syncthreads();

        bf16x8 afh[4], afl[4], bfh[2], bfl[2];
#pragma unroll
        for (int fm = 0; fm < 4; fm++) {
            const int idx = (fm * 16 + lm) * 40 + lk * 8;
            afh[fm] = *(bf16x8*)&Ah[idx];
            afl[fm] = *(bf16x8*)&Al[idx];
        }
#pragma unroll
        for (int fn = 0; fn < 2; fn++) {
            const int idx = (wn + fn * 16 + lm) * 40 + lk * 8;
            bfh[fn] = *(bf16x8*)&Bh[idx];
            bfl[fn] = *(bf16x8*)&Bl[idx];
        }
#pragma unroll
        for (int fm = 0; fm < 4; fm++)
#pragma unroll
            for (int fn = 0; fn < 2; fn++) {
                acc[fm][fn] = __builtin_amdgcn_mfma_f32_16x16x32_bf16(afh[fm], bfh[fn], acc[fm][fn], 0, 0, 0);
                acc[fm][fn] = __builtin_amdgcn_mfma_f32_16x16x32_bf16(afh[fm], bfl[fn], acc[fm][fn], 0, 0, 0);
                acc[fm][fn] = __builtin_amdgcn_mfma_f32_16x16x32_bf16(afl[fm], bfh[fn], acc[fm][fn], 0, 0, 0);
            }
    }

    float* Ps = P + (size_t)s * 64 * N;
#pragma unroll
    for (int fm = 0; fm < 4; fm++)
#pragma unroll
        for (int fn = 0; fn < 2; fn++) {
            const int col = n0 + wn + fn * 16 + lm;
#pragma unroll
            for (int r = 0; r < 4; r++) {
                const int row = fm * 16 + lk * 4 + r;
                Ps[(size_t)row * N + col] = acc[fm][fn][r];
            }
        }
}

// ---------------------------------------------------------------------------
// Fused attention mega-kernel: one block (1024 threads) per batch row b.
// Phase 1: reduce U_h (LDS) + sigmoid gate (LDS) from Wug split-K partials P
//          (+ emb/h copies into xh).
// Phase 2: e[l] = tanh(Ws[b,l,:]+Uh)·Wv + bv  (16 waves × rows, reg-hoisted).
// Phase 3: softmax(e) -> al (LDS) + alphas_out write.
// Phase 4: context d-striped + gate multiply -> xh.
// Replaces reduce_partials + attn_e + ctx_fuse (3 launches -> 1).
// ---------------------------------------------------------------------------
__global__ __launch_bounds__(1024) void attn_mega(
    const float* __restrict__ P, const float* __restrict__ bug,
    const float* __restrict__ Ws, const float* __restrict__ Wv,
    const float* __restrict__ bv, const float* __restrict__ img,
    const float* __restrict__ embt, const int* __restrict__ captions,
    const float* __restrict__ h, float* __restrict__ xh,
    float* __restrict__ alphas_out, int t)
{
    __shared__ float uh[1024];
    __shared__ float gg[2048];
    __shared__ float ee[256];
    __shared__ float red[256];

    const int b = blockIdx.x, tid = threadIdx.x;

    // ---- phase 1: Uh + gate reduce from P; emb/h copies ----
    {
        const float* pb = P + (size_t)b * 3072;
        float v = bug[tid];
        float g0 = bug[1024 + tid];
        float g1 = bug[2048 + tid];
#pragma unroll
        for (int s = 0; s < 8; s++) {
            const float* q = pb + (size_t)s * 64 * 3072;
            v  += q[tid];
            g0 += q[1024 + tid];
            g1 += q[2048 + tid];
        }
        uh[tid] = v;
        gg[tid] = fast_sig(g0);
        gg[tid + 1024] = fast_sig(g1);

        const int tok = (t == 0) ? 10001 : captions[b * 16 + (t - 1)];
        if (tid < EMBD) xh[(size_t)b * 3584 + tid] = embt[(size_t)tok * EMBD + tid];
        xh[(size_t)b * 3584 + 2560 + tid] = h[(size_t)b * RNND + tid];
    }
    __syncthreads();

    // ---- phase 2: e[l] ----
    {
        const int wave = tid >> 6, lane = tid & 63;
        float ur[16], vr[16];
#pragma unroll
        for (int j = 0; j < 4; j++) {
            const int k = lane * 4 + j * 256;
            float4 u4 = *(const float4*)&uh[k];
            float4 v4 = *(const float4*)(Wv + k);
            ur[j*4+0] = u4.x; ur[j*4+1] = u4.y; ur[j*4+2] = u4.z; ur[j*4+3] = u4.w;
            vr[j*4+0] = v4.x; vr[j*4+1] = v4.y; vr[j*4+2] = v4.z; vr[j*4+3] = v4.w;
        }
        for (int l = wave; l < LIMG; l += 16) {
            const float* wrow = Ws + ((size_t)b * LIMG + l) * RNND;
            float acc = 0.f;
#pragma unroll
            for (int j = 0; j < 4; j++) {
                const int k = lane * 4 + j * 256;
                float4 wq = *(const float4*)(wrow + k);
                acc += fast_tanh(wq.x + ur[j*4+0]) * vr[j*4+0]
                     + fast_tanh(wq.y + ur[j*4+1]) * vr[j*4+1]
                     + fast_tanh(wq.z + ur[j*4+2]) * vr[j*4+2]
                     + fast_tanh(wq.w + ur[j*4+3]) * vr[j*4+3];
            }
#pragma unroll
            for (int off = 32; off > 0; off >>= 1) acc += __shfl_down(acc, off);
            if (lane == 0) ee[l] = acc + bv[0];
        }
    }
    __syncthreads();

    // ---- phase 3: softmax over ee[0..195], write alphas ----
    {
        if (tid < 256) red[tid] = (tid < LIMG) ? ee[tid] : -3.0e38f;
        __syncthreads();
        for (int s = 128; s > 0; s >>= 1) {
            if (tid < s) red[tid] = fmaxf(red[tid], red[tid + s]);
            __syncthreads();
        }
        const float mx = red[0];
        __syncthreads();
        float ex = 0.f;
        if (tid < LIMG) ex = __expf(ee[tid] - mx);
        if (tid < 256) red[tid] = ex;
        __syncthreads();
        for (int s = 128; s > 0; s >>= 1) {
            if (tid < s) red[tid] += red[tid + s];
            __syncthreads();
        }
        const float inv = 1.f / red[0];
        __syncthreads();
        if (tid < LIMG) {
            const float a = ex * inv;
            ee[tid] = a;
            alphas_out[(size_t)b * (TSTEPS * LIMG) + t * LIMG + tid] = a;
        }
    }
    __syncthreads();

    // ---- phase 4: context + gate ----
    {
        const int d0 = tid * 2;
        const float* ib = img + (size_t)b * LIMG * DIMG + d0;
        float a0 = 0.f, a1 = 0.f;
#pragma unroll 4
        for (int l = 0; l < LIMG; l++) {
            float2 q = *(const float2*)(ib + (size_t)l * DIMG);
            a0 = fmaf(ee[l], q.x, a0);
            a1 = fmaf(ee[l], q.y, a1);
        }
        xh[(size_t)b * 3584 + EMBD + d0]     = gg[d0] * a0;
        xh[(size_t)b * 3584 + EMBD + d0 + 1] = gg[d0 + 1] * a1;
    }
}

// ---------------------------------------------------------------------------
// fp32 tiled GEMM (h0/c0 init + fallback)
// ---------------------------------------------------------------------------
__global__ __launch_bounds__(256) void gemm64(
    const float* __restrict__ A, const float* __restrict__ B,
    const float* __restrict__ bias, float* __restrict__ C,
    int N, int K, int Kc, int ldc, int act, int direct)
{
    __shared__ float As[16][64];
    __shared__ float Bs[16][68];

    const int tid = threadIdx.x;
    const int n0  = blockIdx.x * 64;
    const int m0  = blockIdx.y * 64;
    const int s   = blockIdx.z;
    const int kb  = s * Kc;
    const int ke  = min(K, kb + Kc);

    const int tm = (tid >> 4) << 2;
    const int tn = (tid & 15) << 2;

    float acc[4][4];
#pragma unroll
    for (int i = 0; i < 4; i++)
#pragma unroll
        for (int j = 0; j < 4; j++) acc[i][j] = 0.f;

    const int a_m = tid >> 2;
    const int a_k = (tid & 3) << 2;
    const int b_k = tid >> 4;
    const int b_n = (tid & 15) << 2;
    const bool n4 = ((N & 3) == 0);

    for (int k0 = kb; k0 < ke; k0 += 16) {
        float4 av = *(const float4*)(A + (size_t)(m0 + a_m) * K + (k0 + a_k));
        float4 bv;
        {
            const int nn = n0 + b_n;
            const float* brow = B + (size_t)(k0 + b_k) * N;
            if (n4) {
                bv = (nn < N) ? *(const float4*)(brow + nn) : make_float4(0.f,0.f,0.f,0.f);
            } else {
                bv.x = (nn + 0 < N) ? brow[nn + 0] : 0.f;
                bv.y = (nn + 1 < N) ? brow[nn + 1] : 0.f;
                bv.z = (nn + 2 < N) ? brow[nn + 2] : 0.f;
                bv.w = (nn + 3 < N) ? brow[nn + 3] : 0.f;
            }
        }
        __syncthreads();
        As[a_k + 0][a_m] = av.x;
        As[a_k + 1][a_m] = av.y;
        As[a_k + 2][a_m] = av.z;
        As[a_k + 3][a_m] = av.w;
        *(float4*)&Bs[b_k][b_n] = bv;
        __syncthreads();
#pragma unroll
        for (int k = 0; k < 16; k++) {
            float4 a4 = *(const float4*)&As[k][tm];
            float4 b4 = *(const float4*)&Bs[k][tn];
            acc[0][0] = fmaf(a4.x, b4.x, acc[0][0]);
            acc[0][1] = fmaf(a4.x, b4.y, acc[0][1]);
            acc[0][2] = fmaf(a4.x, b4.z, acc[0][2]);
            acc[0][3] = fmaf(a4.x, b4.w, acc[0][3]);
            acc[1][0] = fmaf(a4.y, b4.x, acc[1][0]);
            acc[1][1] = fmaf(a4.y, b4.y, acc[1][1]);
            acc[1][2] = fmaf(a4.y, b4.z, acc[1][2]);
            acc[1][3] = fmaf(a4.y, b4.w, acc[1][3]);
            acc[2][0] = fmaf(a4.z, b4.x, acc[2][0]);
            acc[2][1] = fmaf(a4.z, b4.y, acc[2][1]);
            acc[2][2] = fmaf(a4.z, b4.z, acc[2][2]);
            acc[2][3] = fmaf(a4.z, b4.w, acc[2][3]);
            acc[3][0] = fmaf(a4.w, b4.x, acc[3][0]);
            acc[3][1] = fmaf(a4.w, b4.y, acc[3][1]);
            acc[3][2] = fmaf(a4.w, b4.z, acc[3][2]);
            acc[3][3] = fmaf(a4.w, b4.w, acc[3][3]);
        }
    }

    if (direct) {
#pragma unroll
        for (int i = 0; i < 4; i++) {
            const int m = m0 + tm + i;
            const size_t row = (size_t)m * ldc;
#pragma unroll
            for (int j = 0; j < 4; j++) {
                const int n = n0 + tn + j;
                if (n < N) {
                    float v = acc[i][j] + (bias ? bias[n] : 0.f);
                    if (act == 1) v = fast_tanh(v);
                    else if (act == 2) v = fast_sig(v);
                    C[row + n] = v;
                }
            }
        }
    } else {
        float* Pp = C + (size_t)s * 64 * N;
#pragma unroll
        for (int i = 0; i < 4; i++) {
#pragma unroll
            for (int j = 0; j < 4; j++) {
                const int n = n0 + tn + j;
                if (n < N) Pp[(size_t)(tm + i) * N + n] = acc[i][j];
            }
        }
    }
}

// fallback big GEMM (round-3, validated)
__global__ __launch_bounds__(256) void gemm_mfma3(
    const float* __restrict__ A, const float* __restrict__ B,
    const float* __restrict__ bias, float* __restrict__ C,
    int M, int N, int K, int lda, int ldb, int ldc, int pmap)
{
    __shared__ short Ah[128 * 40], Al[128 * 40];
    __shared__ short Bh[128 * 40], Bl[128 * 40];

    const int tid = threadIdx.x;
    const int n0  = blockIdx.x * 128;
    const int m0  = blockIdx.y * 128;

    const int lane = tid & 63;
    const int w    = tid >> 6;
    const int wm   = (w >> 1) * 64;
    const int wn   = (w & 1) * 64;
    const int lm   = lane & 15;
    const int lk   = lane >> 4;

    const int ar = tid >> 1;
    const int ac = (tid & 1) * 16;
    const int kb = (tid & 15) * 2;
    const int c8 = (tid >> 4) * 8;

    const bool bvec = ((ldb & 3) == 0) && (n0 + 128 <= N);

    f32x4 acc[4][4];
#pragma unroll
    for (int i = 0; i < 4; i++)
#pragma unroll
        for (int j = 0; j < 4; j++) acc[i][j] = (f32x4)0.f;

    for (int k0 = 0; k0 < K; k0 += 32) {
        float f[16];
        if (m0 + ar < M) {
            const float* ap = A + (size_t)(m0 + ar) * lda + (k0 + ac);
            float4 q0 = *(const float4*)(ap);
            float4 q1 = *(const float4*)(ap + 4);
            float4 q2 = *(const float4*)(ap + 8);
            float4 q3 = *(const float4*)(ap + 12);
            f[0]=q0.x; f[1]=q0.y; f[2]=q0.z; f[3]=q0.w;
            f[4]=q1.x; f[5]=q1.y; f[6]=q1.z; f[7]=q1.w;
            f[8]=q2.x; f[9]=q2.y; f[10]=q2.z; f[11]=q2.w;
            f[12]=q3.x; f[13]=q3.y; f[14]=q3.z; f[15]=q3.w;
        } else {
#pragma unroll
            for (int j = 0; j < 16; j++) f[j] = 0.f;
        }
        bf16x8 h0, h1, l0, l1;
#pragma unroll
        for (int j = 0; j < 8; j++) {
            short hh, ll;
            split_bf(f[j], hh, ll);     h0[j] = hh; l0[j] = ll;
            split_bf(f[8 + j], hh, ll); h1[j] = hh; l1[j] = ll;
        }
        float g0[8], g1[8];
        if (bvec) {
            const float* bp0 = B + (size_t)(k0 + kb) * ldb + (n0 + c8);
            const float* bp1 = bp0 + ldb;
            float4 q0 = *(const float4*)(bp0);
            float4 q1 = *(const float4*)(bp0 + 4);
            float4 q2 = *(const float4*)(bp1);
            float4 q3 = *(const float4*)(bp1 + 4);
            g0[0]=q0.x; g0[1]=q0.y; g0[2]=q0.z; g0[3]=q0.w;
            g0[4]=q1.x; g0[5]=q1.y; g0[6]=q1.z; g0[7]=q1.w;
            g1[0]=q2.x; g1[1]=q2.y; g1[2]=q2.z; g1[3]=q2.w;
            g1[4]=q3.x; g1[5]=q3.y; g1[6]=q3.z; g1[7]=q3.w;
        } else {
            const float* bp0 = B + (size_t)(k0 + kb) * ldb;
            const float* bp1 = bp0 + ldb;
#pragma unroll
            for (int j = 0; j < 8; j++) {
                const int nn = n0 + c8 + j;
                g0[j] = (nn < N) ? bp0[nn] : 0.f;
                g1[j] = (nn < N) ? bp1[nn] : 0.f;
            }
        }
        __syncthreads();
        *(bf16x8*)&Ah[ar * 40 + ac]     = h0;
        *(bf16x8*)&Ah[ar * 40 + ac + 8] = h1;
        *(bf16x8*)&Al[ar * 40 + ac]     = l0;
        *(bf16x8*)&Al[ar * 40 + ac + 8] = l1;
#pragma unroll
        for (int j = 0; j < 8; j++) {
            short ha, la, hb, lb;
            split_bf(g0[j], ha, la);
            split_bf(g1[j], hb, lb);
            const int ci = (c8 + j) * 40 + kb;
            *(int*)&Bh[ci] = (int)((unsigned short)ha | ((unsigned)(unsigned short)hb << 16));
            *(int*)&Bl[ci] = (int)((unsigned short)la | ((unsigned)(unsigned short)lb << 16));
        }
        __syncthreads();

        bf16x8 afh[4], afl[4], bfh[4], bfl[4];
#pragma unroll
        for (int fm = 0; fm < 4; fm++) {
            const int idx = (wm + fm * 16 + lm) * 40 + lk * 8;
            afh[fm] = *(bf16x8*)&Ah[idx];
            afl[fm] = *(bf16x8*)&Al[idx];
        }
#pragma unroll
        for (int fn = 0; fn < 4; fn++) {
            const int idx = (wn + fn * 16 + lm) * 40 + lk * 8;
            bfh[fn] = *(bf16x8*)&Bh[idx];
            bfl[fn] = *(bf16x8*)&Bl[idx];
        }
#pragma unroll
        for (int fm = 0; fm < 4; fm++)
#pragma unroll
            for (int fn = 0; fn < 4; fn++) {
                acc[fm][fn] = __builtin_amdgcn_mfma_f32_16x16x32_bf16(afh[fm], bfh[fn], acc[fm][fn], 0, 0, 0);
                acc[fm][fn] = __builtin_amdgcn_mfma_f32_16x16x32_bf16(afh[fm], bfl[fn], acc[fm][fn], 0, 0, 0);
                acc[fm][fn] = __builtin_amdgcn_mfma_f32_16x16x32_bf16(afl[fm], bfh[fn], acc[fm][fn], 0, 0, 0);
            }
    }

#pragma unroll
    for (int fm = 0; fm < 4; fm++) {
#pragma unroll
        for (int fn = 0; fn < 4; fn++) {
            const int col = n0 + wn + fn * 16 + lm;
            if (col >= N) continue;
            const float bb = bias ? bias[col] : 0.f;
#pragma unroll
            for (int r = 0; r < 4; r++) {
                const int row = m0 + wm + fm * 16 + lk * 4 + r;
                if (row >= M) continue;
                const size_t orow = pmap ? (size_t)((row & 63) * TSTEPS + (row >> 6))
                                         : (size_t)row;
                C[orow * ldc + col] = acc[fm][fn][r] + bb;
            }
        }
    }
}

__global__ __launch_bounds__(256) void reduce_partials(
    const float* __restrict__ P, int S, int N,
    const float* __restrict__ bias, float* __restrict__ C, int ldc, int act)
{
    const int idx = blockIdx.x * 256 + threadIdx.x;
    const int total = 64 * N;
    if (idx >= total) return;
    const int m = idx / N;
    const int n = idx - m * N;
    float v = bias ? bias[n] : 0.f;
    for (int s = 0; s < S; s++) v += P[(size_t)s * total + idx];
    if (act == 1) v = fast_tanh(v);
    else if (act == 2) v = fast_sig(v);
    else if (act == 3 && n >= RNND) v = fast_sig(v);
    C[(size_t)m * ldc + n] = v;
}

__global__ __launch_bounds__(256) void reduce_lstm(
    const float* __restrict__ P, int S, const float* __restrict__ bsum,
    float* __restrict__ hn, float* __restrict__ c,
    short* __restrict__ hbh, short* __restrict__ hbl)
{
    const int idx = blockIdx.x * 256 + threadIdx.x;
    const int b = idx >> 10, r = idx & 1023;
    const float* pb = P + (size_t)b * 4096;
    float gi = bsum[r], gf = bsum[1024 + r], gg = bsum[2048 + r], go = bsum[3072 + r];
    for (int s = 0; s < S; s++) {
        const float* q = pb + (size_t)s * 64 * 4096;
        gi += q[r]; gf += q[1024 + r]; gg += q[2048 + r]; go += q[3072 + r];
    }
    const float ig = fast_sig(gi);
    const float fg = fast_sig(gf);
    const float g2 = fast_tanh(gg);
    const float og = fast_sig(go);
    const float cn = fg * c[idx] + ig * g2;
    const float hv = og * fast_tanh(cn);
    c[idx]  = cn;
    hn[idx] = hv;
    if (hbh) {
        short hi, lo;
        split_bf(hv, hi, lo);
        hbh[idx] = hi;
        hbl[idx] = lo;
    }
}

__global__ __launch_bounds__(256) void mean_img(
    const float* __restrict__ img, float* __restrict__ avg)
{
    const int b = blockIdx.x;
    const int d = blockIdx.y * 256 + threadIdx.x;
    const float* p = img + (size_t)b * LIMG * DIMG + d;
    float s = 0.f;
    for (int l = 0; l < LIMG; l++) s += p[(size_t)l * DIMG];
    avg[(size_t)b * DIMG + d] = s * (1.f / 196.f);
}

__global__ __launch_bounds__(256) void concat_w(
    const float* __restrict__ WU, const float* __restrict__ Wfb,
    float* __restrict__ Wug)
{
    const int idx = blockIdx.x * 256 + threadIdx.x;
    if (idx >= 1024 * 3072) return;
    const int k = idx / 3072;
    const int j = idx - k * 3072;
    Wug[idx] = (j < 1024) ? WU[(size_t)k * 1024 + j] : Wfb[(size_t)k * 2048 + (j - 1024)];
}

__global__ __launch_bounds__(256) void concat_b(
    const float* __restrict__ bU, const float* __restrict__ bfb,
    const float* __restrict__ bih, const float* __restrict__ bhh,
    float* __restrict__ bug, float* __restrict__ bsum)
{
    const int j = blockIdx.x * 256 + threadIdx.x;
    if (j < 3072) bug[j] = (j < 1024) ? bU[j] : bfb[j - 1024];
    if (j < 4096) bsum[j] = bih[j] + bhh[j];
}

__global__ __launch_bounds__(256) void attn_e(
    const float* __restrict__ Ws, const float* __restrict__ ug,
    const float* __restrict__ Wv, const float* __restrict__ bv,
    float* __restrict__ e)
{
    const int wv   = (blockIdx.x << 2) + (threadIdx.x >> 6);
    const int lane = threadIdx.x & 63;
    const int b    = wv / LIMG;
    const float* wrow = Ws + (size_t)wv * RNND;
    const float* urow = ug + (size_t)b * 3072;
    float acc = 0.f;
#pragma unroll
    for (int k = lane * 4; k < RNND; k += 256) {
        float4 wq = *(const float4*)(wrow + k);
        float4 uq = *(const float4*)(urow + k);
        float4 vq = *(const float4*)(Wv + k);
        acc += fast_tanh(wq.x + uq.x) * vq.x + fast_tanh(wq.y + uq.y) * vq.y
             + fast_tanh(wq.z + uq.z) * vq.z + fast_tanh(wq.w + uq.w) * vq.w;
    }
#pragma unroll
    for (int off = 32; off > 0; off >>= 1) acc += __shfl_down(acc, off);
    if (lane == 0) e[wv] = acc + bv[0];
}

__global__ __launch_bounds__(256) void softmax_alpha(
    const float* __restrict__ e, float* __restrict__ alpha,
    float* __restrict__ alphas_out, int t)
{
    __shared__ float red[256];
    const int b = blockIdx.x, tid = threadIdx.x;
    const float v = (tid < LIMG) ? e[b * LIMG + tid] : -3.0e38f;
    red[tid] = v; __syncthreads();
    for (int s = 128; s > 0; s >>= 1) {
        if (tid < s) red[tid] = fmaxf(red[tid], red[tid + s]);
        __syncthreads();
    }
    const float mx = red[0]; __syncthreads();
    const float ex = (tid < LIMG) ? __expf(v - mx) : 0.f;
    red[tid] = ex; __syncthreads();
    for (int s = 128; s > 0; s >>= 1) {
        if (tid < s) red[tid] += red[tid + s];
        __syncthreads();
    }
    const float inv = 1.f / red[0];
    if (tid < LIMG) {
        const float a = ex * inv;
        alpha[b * LIMG + tid] = a;
        alphas_out[(size_t)b * (TSTEPS * LIMG) + t * LIMG + tid] = a;
    }
}

__global__ __launch_bounds__(128) void assemble_x(
    const float* __restrict__ img, const float* __restrict__ alpha,
    const float* __restrict__ ug, const float* __restrict__ emb,
    const int* __restrict__ captions, const float* __restrict__ h,
    float* __restrict__ x, int t, int stride)
{
    const int b = blockIdx.x, y = blockIdx.y, tid = threadIdx.x;
    if (y < 4) {
        const int tok = (t == 0) ? 10001 : captions[b * 16 + (t - 1)];
        const int j = y * 128 + tid;
        x[(size_t)b * stride + j] = emb[(size_t)tok * EMBD + j];
    } else if (y < 20) {
        __shared__ float al[LIMG];
        for (int i = tid; i < LIMG; i += 128) al[i] = alpha[b * LIMG + i];
        __syncthreads();
        const int d = (y - 4) * 128 + tid;
        const float* ib = img + (size_t)b * LIMG * DIMG + d;
        float accv = 0.f;
#pragma unroll 4
        for (int l = 0; l < LIMG; l++) accv = fmaf(al[l], ib[(size_t)l * DIMG], accv);
        const float g = ug[(size_t)b * 3072 + 1024 + d];
        x[(size_t)b * stride + EMBD + d] = g * accv;
    } else {
        const int j = (y - 20) * 128 + tid;
        x[(size_t)b * stride + 2560 + j] = h[(size_t)b * RNND + j];
    }
}

extern "C" void kernel_launch(void* const* d_in, const int* in_sizes, int n_in,
                              void* d_out, int out_size, void* d_ws, size_t ws_size,
                              hipStream_t stream)
{
    const float* img      = (const float*)d_in[0];
    const int*   captions = (const int*)d_in[1];
    const float* emb      = (const float*)d_in[2];
    const float* Wih      = (const float*)d_in[3];
    const float* Whh      = (const float*)d_in[4];
    const float* bih      = (const float*)d_in[5];
    const float* bhh      = (const float*)d_in[6];
    const float* Wh0      = (const float*)d_in[7];
    const float* bh0      = (const float*)d_in[8];
    const float* Wc0      = (const float*)d_in[9];
    const float* bc0      = (const float*)d_in[10];
    const float* Wfb      = (const float*)d_in[11];
    const float* bfb      = (const float*)d_in[12];
    const float* Wout     = (const float*)d_in[13];
    const float* bout     = (const float*)d_in[14];
    const float* WU       = (const float*)d_in[15];
    const float* bU       = (const float*)d_in[16];
    const float* WW       = (const float*)d_in[17];
    const float* bW       = (const float*)d_in[18];
    const float* Wv       = (const float*)d_in[19];
    const float* bv       = (const float*)d_in[20];

    float* preds      = (float*)d_out;
    float* alphas_out = preds + (size_t)NB * TSTEPS * VOUTD;

    const size_t NEED = 190000000;

    if (ws_size >= NEED) {
        float* w = (float*)d_ws;
        float* Ws    = w; w += (size_t)12544 * 1024;
        float* ug    = w; w += (size_t)64 * 3072;
        float* P     = w; w += (size_t)8 * 64 * 4096;
        float* e     = w; w += (size_t)64 * LIMG;
        float* alpha = w; w += (size_t)64 * LIMG;
        float* xh    = w; w += (size_t)64 * 3584;
        float* h     = w; w += (size_t)64 * RNND;
        float* c     = w; w += (size_t)64 * RNND;
        float* avg   = w; w += (size_t)64 * DIMG;
        float* bsum  = w; w += 4096;
        float* bug   = w; w += 3072;
        short* u = (short*)w;
        short* Hbh     = u; u += (size_t)1280 * 1024;
        short* Hbl     = u; u += (size_t)1280 * 1024;
        short* WWTh    = u; u += (size_t)1024 * 2048;
        short* WWTl    = u; u += (size_t)1024 * 2048;
        short* WugTh   = u; u += (size_t)3072 * 1024;
        short* WugTl   = u; u += (size_t)3072 * 1024;
        short* WfullTh = u; u += (size_t)4096 * 3584;
        short* WfullTl = u; u += (size_t)4096 * 3584;
        short* WoutTh  = u; u += (size_t)10112 * 1024;
        short* WoutTl  = u; u += (size_t)10112 * 1024;

        mean_img<<<dim3(NB, 8), 256, 0, stream>>>(img, avg);
        gemm64<<<dim3(16, 1, 8), 256, 0, stream>>>(avg, Wh0, nullptr, P, 1024, 2048, 256, 0, 0, 0);
        reduce_partials<<<256, 256, 0, stream>>>(P, 8, 1024, bh0, h, 1024, 1);
        gemm64<<<dim3(16, 1, 8), 256, 0, stream>>>(avg, Wc0, nullptr, P, 1024, 2048, 256, 0, 0, 0);
        reduce_partials<<<256, 256, 0, stream>>>(P, 8, 1024, bc0, c, 1024, 1);
        concat_b<<<16, 256, 0, stream>>>(bU, bfb, bih, bhh, bug, bsum);

        tsplit<<<dim3(32, 16), 256, 0, stream>>>(WW, 1024, WW, 1024, WWTh, WWTl, 1024, 2048, 2048, 0);
        tsplit<<<dim3(16, 48), 256, 0, stream>>>(WU, 1024, Wfb, 2048, WugTh, WugTl, 3072, 1024, 1024, 1024);
        tsplit<<<dim3(56, 64), 256, 0, stream>>>(Wih, 4096, Whh, 4096, WfullTh, WfullTl, 4096, 3584, 2560, 0);
        tsplit<<<dim3(16, 157), 256, 0, stream>>>(Wout, VOUTD, Wout, VOUTD, WoutTh, WoutTl, VOUTD, 1024, 1024, 0);

        // W_s = img @ WW + bW : 64x128 tiles, grid (8, 196)
        gemm_mt<<<dim3(8, 196), 256, 0, stream>>>(img, nullptr, nullptr, WWTh, WWTl,
                                                  bW, Ws, 1024, 2048, 2048, 2048, 1024, 0);

        for (int t = 0; t < TSTEPS; t++) {
            // [U_h | gate] split-K partials
            gemm_sk<<<dim3(24, 1, 8), 256, 0, stream>>>(h, WugTh, WugTl, P, 3072, 1024, 1024, 1024, 128);
            // fused: Uh+gate reduce, e, softmax, alphas, context, x assembly
            attn_mega<<<NB, 1024, 0, stream>>>(P, bug, Ws, Wv, bv, img, emb, captions,
                                               h, xh, alphas_out, t);
            // gates = xh @ [Wih;Whh]^T split-K
            gemm_sk<<<dim3(32, 1, 7), 256, 0, stream>>>(xh, WfullTh, WfullTl, P, 4096, 3584, 3584, 3584, 512);
            reduce_lstm<<<256, 256, 0, stream>>>(P, 7, bsum, h, c,
                                                 Hbh + (size_t)(t + 1) * 65536,
                                                 Hbl + (size_t)(t + 1) * 65536);
        }

        // preds: 64x128 tiles, grid (79, 17), pmap output
        gemm_mt<<<dim3(79, 17), 256, 0, stream>>>(nullptr, Hbh + 65536, Hbl + 65536,
                                                  WoutTh, WoutTl, bout, preds,
                                                  VOUTD, 1024, 1024, 1024, VOUTD, 1);
    } else {
        float* w = (float*)d_ws;
        float* Ws    = w; w += (size_t)12544 * 1024;
        float* ug    = w; w += (size_t)64 * 3072;
        float* P     = w; w += (size_t)12 * 64 * 4096;
        float* e     = w; w += (size_t)64 * LIMG;
        float* alpha = w; w += (size_t)64 * LIMG;
        float* x     = w; w += (size_t)64 * 2560;
        float* Hh    = w; w += (size_t)18 * 64 * RNND;
        float* c     = w; w += (size_t)64 * RNND;
        float* avg   = w; w += (size_t)64 * DIMG;
        float* bsum  = w; w += 4096;
        float* Wug   = w; w += (size_t)1024 * 3072;
        float* bug   = w; w += 3072;

        mean_img<<<dim3(NB, 8), 256, 0, stream>>>(img, avg);
        gemm64<<<dim3(16, 1, 8), 256, 0, stream>>>(avg, Wh0, nullptr, P, 1024, 2048, 256, 0, 0, 0);
        reduce_partials<<<256, 256, 0, stream>>>(P, 8, 1024, bh0, Hh, 1024, 1);
        gemm64<<<dim3(16, 1, 8), 256, 0, stream>>>(avg, Wc0, nullptr, P, 1024, 2048, 256, 0, 0, 0);
        reduce_partials<<<256, 256, 0, stream>>>(P, 8, 1024, bc0, c, 1024, 1);
        concat_b<<<16, 256, 0, stream>>>(bU, bfb, bih, bhh, bug, bsum);
        concat_w<<<12288, 256, 0, stream>>>(WU, Wfb, Wug);
        gemm_mfma3<<<dim3(8, 98), 256, 0, stream>>>(img, WW, bW, Ws,
                                                    12544, 1024, 2048, 2048, 1024, 1024, 0);
        for (int t = 0; t < TSTEPS; t++) {
            const float* hc = Hh + (size_t)t * 64 * RNND;
            float*       hn = Hh + (size_t)(t + 1) * 64 * RNND;
            gemm64<<<dim3(48, 1, 8), 256, 0, stream>>>(hc, Wug, nullptr, P, 3072, 1024, 128, 0, 0, 0);
            reduce_partials<<<768, 256, 0, stream>>>(P, 8, 3072, bug, ug, 3072, 3);
            attn_e<<<3136, 256, 0, stream>>>(Ws, ug, Wv, bv, e);
            softmax_alpha<<<NB, 256, 0, stream>>>(e, alpha, alphas_out, t);
            assemble_x<<<dim3(NB, 20), 128, 0, stream>>>(img, alpha, ug, emb, captions, hc, x, t, 2560);
            gemm64<<<dim3(64, 1, 8), 256, 0, stream>>>(x, Wih, nullptr, P, 4096, 2560, 320, 0, 0, 0);
            gemm64<<<dim3(64, 1, 4), 256, 0, stream>>>(hc, Whh, nullptr, P + (size_t)8 * 64 * 4096,
                                                       4096, 1024, 256, 0, 0, 0);
            reduce_lstm<<<256, 256, 0, stream>>>(P, 12, bsum, hn, c, nullptr, nullptr);
        }
        gemm_mfma3<<<dim3(79, 9), 256, 0, stream>>>(Hh + (size_t)64 * RNND, Wout, bout, preds,
                                                    TSTEPS * 64, VOUTD, 1024, 1024, VOUTD, VOUTD, 1);
    }
}

// Round 12
// 1902.701 us; speedup vs baseline: 1.1891x; 1.1891x over previous
//
#include <hip/hip_runtime.h>
#include <cstdint>

#define NB    64
#define LIMG  196
#define DIMG  2048
#define RNND  1024
#define EMBD  512
#define TSTEPS 17
#define VOUTD 10003

typedef short bf16x8 __attribute__((ext_vector_type(8)));
typedef float f32x4  __attribute__((ext_vector_type(4)));

__device__ __forceinline__ float fast_sig(float x) {
    return 1.f / (1.f + __expf(-x));
}
__device__ __forceinline__ float fast_tanh(float x) {
    float ax = fabsf(x);
    float e  = __expf(2.f * ax);
    float r  = 1.f - 2.f / (e + 1.f);
    return copysignf(r, x);
}
__device__ __forceinline__ void split_bf(float x, short& hi, short& lo) {
    unsigned u  = __float_as_uint(x);
    unsigned hb = u & 0xffff0000u;
    hi = (short)(u >> 16);
    float r = x - __uint_as_float(hb);
    lo = (short)(__float_as_uint(r) >> 16);
}

// ---------------------------------------------------------------------------
// Transpose + bf16 hi/lo split of weights
// ---------------------------------------------------------------------------
__global__ __launch_bounds__(256) void tsplit(
    const float* __restrict__ S1, int ld1,
    const float* __restrict__ S2, int ld2,
    short* __restrict__ outh, short* __restrict__ outl,
    int N, int K, int ksplit, int nsplit)
{
    __shared__ float T[64][65];
    const int k0 = blockIdx.x * 64, n0 = blockIdx.y * 64;
    const int tid = threadIdx.x;
    const int rr = tid >> 2;
    const int cc = (tid & 3) * 16;
    const int kk = k0 + rr;
    const int nn = n0 + cc;
    const float* rp; int col;
    if (nsplit > 0) {
        if (nn >= nsplit) { rp = S2 + (size_t)kk * ld2; col = nn - nsplit; }
        else              { rp = S1 + (size_t)kk * ld1; col = nn; }
    } else {
        if (kk < ksplit)  { rp = S1 + (size_t)kk * ld1; col = nn; }
        else              { rp = S2 + (size_t)(kk - ksplit) * ld2; col = nn; }
    }
#pragma unroll
    for (int j = 0; j < 16; j++)
        T[rr][cc + j] = (nn + j < N) ? rp[col + j] : 0.f;
    __syncthreads();
    const int wn = tid >> 2;
    const int wk = (tid & 3) * 16;
    const int gn = n0 + wn;
    if (gn >= N) return;
    bf16x8 h0, h1, l0, l1;
#pragma unroll
    for (int j = 0; j < 8; j++) {
        short hh, ll;
        split_bf(T[wk + j][wn], hh, ll);     h0[j] = hh; l0[j] = ll;
        split_bf(T[wk + 8 + j][wn], hh, ll); h1[j] = hh; l1[j] = ll;
    }
    const size_t o = (size_t)gn * K + k0 + wk;
    *(bf16x8*)&outh[o]     = h0;
    *(bf16x8*)&outh[o + 8] = h1;
    *(bf16x8*)&outl[o]     = l0;
    *(bf16x8*)&outl[o + 8] = l1;
}

// ---------------------------------------------------------------------------
// m-tiled 64x128 bf16x3 MFMA GEMM. grid (N/128 ceil, M/64).
// A: f32 (Af) split on the fly, or bf16 pair. B pre-split [N][K] bf16 pair.
// Direct epilogue: bias + optional pmap (row -> (row&63)*17 + (row>>6)).
// Register prefetch of next K-tile.
// ---------------------------------------------------------------------------
__global__ __launch_bounds__(256) void gemm_mt(
    const float* __restrict__ Af,
    const short* __restrict__ Ah16, const short* __restrict__ Al16,
    const short* __restrict__ Bh16, const short* __restrict__ Bl16,
    const float* __restrict__ bias, float* __restrict__ C,
    int N, int K, int lda, int ldb, int ldc, int pmap)
{
    __shared__ short Ah[64 * 40], Al[64 * 40];
    __shared__ short Bh[128 * 40], Bl[128 * 40];

    const int tid = threadIdx.x;
    const int n0  = blockIdx.x * 128;
    const int m0  = blockIdx.y * 64;

    const int lane = tid & 63;
    const int w    = tid >> 6;
    const int wn   = w * 32;
    const int lm   = lane & 15;
    const int lk   = lane >> 4;

    const int a_r = tid >> 2;
    const int a_c = (tid & 3) * 8;
    const int b_r = tid >> 1;
    const int b_c = (tid & 1) * 16;

    f32x4 acc[4][2];
#pragma unroll
    for (int i = 0; i < 4; i++)
#pragma unroll
        for (int j = 0; j < 2; j++) acc[i][j] = (f32x4)0.f;

    bf16x8 rah, ral, rbh0, rbh1, rbl0, rbl1;
    auto load_tile = [&](int k0) {
        if (Af) {
            const float* ap = Af + (size_t)(m0 + a_r) * lda + (k0 + a_c);
            float4 q0 = *(const float4*)(ap);
            float4 q1 = *(const float4*)(ap + 4);
            float f[8] = {q0.x, q0.y, q0.z, q0.w, q1.x, q1.y, q1.z, q1.w};
#pragma unroll
            for (int j = 0; j < 8; j++) {
                short hh, ll;
                split_bf(f[j], hh, ll); rah[j] = hh; ral[j] = ll;
            }
        } else {
            rah = *(const bf16x8*)(Ah16 + (size_t)(m0 + a_r) * lda + (k0 + a_c));
            ral = *(const bf16x8*)(Al16 + (size_t)(m0 + a_r) * lda + (k0 + a_c));
        }
        const short* pb = Bh16 + (size_t)(n0 + b_r) * ldb + (k0 + b_c);
        rbh0 = *(const bf16x8*)pb; rbh1 = *(const bf16x8*)(pb + 8);
        const short* qb = Bl16 + (size_t)(n0 + b_r) * ldb + (k0 + b_c);
        rbl0 = *(const bf16x8*)qb; rbl1 = *(const bf16x8*)(qb + 8);
    };

    load_tile(0);
    for (int k0 = 0; k0 < K; k0 += 32) {
        __syncthreads();
        *(bf16x8*)&Ah[a_r * 40 + a_c] = rah;
        *(bf16x8*)&Al[a_r * 40 + a_c] = ral;
        *(bf16x8*)&Bh[b_r * 40 + b_c]     = rbh0;
        *(bf16x8*)&Bh[b_r * 40 + b_c + 8] = rbh1;
        *(bf16x8*)&Bl[b_r * 40 + b_c]     = rbl0;
        *(bf16x8*)&Bl[b_r * 40 + b_c + 8] = rbl1;
        __syncthreads();
        if (k0 + 32 < K) load_tile(k0 + 32);   // prefetch hides under MFMAs

        bf16x8 afh[4], afl[4], bfh[2], bfl[2];
#pragma unroll
        for (int fm = 0; fm < 4; fm++) {
            const int idx = (fm * 16 + lm) * 40 + lk * 8;
            afh[fm] = *(bf16x8*)&Ah[idx];
            afl[fm] = *(bf16x8*)&Al[idx];
        }
#pragma unroll
        for (int fn = 0; fn < 2; fn++) {
            const int idx = (wn + fn * 16 + lm) * 40 + lk * 8;
            bfh[fn] = *(bf16x8*)&Bh[idx];
            bfl[fn] = *(bf16x8*)&Bl[idx];
        }
#pragma unroll
        for (int fm = 0; fm < 4; fm++)
#pragma unroll
            for (int fn = 0; fn < 2; fn++) {
                acc[fm][fn] = __builtin_amdgcn_mfma_f32_16x16x32_bf16(afh[fm], bfh[fn], acc[fm][fn], 0, 0, 0);
                acc[fm][fn] = __builtin_amdgcn_mfma_f32_16x16x32_bf16(afh[fm], bfl[fn], acc[fm][fn], 0, 0, 0);
                acc[fm][fn] = __builtin_amdgcn_mfma_f32_16x16x32_bf16(afl[fm], bfh[fn], acc[fm][fn], 0, 0, 0);
            }
    }

#pragma unroll
    for (int fm = 0; fm < 4; fm++)
#pragma unroll
        for (int fn = 0; fn < 2; fn++) {
            const int col = n0 + wn + fn * 16 + lm;
            if (col >= N) continue;
            const float bb = bias ? bias[col] : 0.f;
#pragma unroll
            for (int r = 0; r < 4; r++) {
                const int row = m0 + fm * 16 + lk * 4 + r;
                const size_t orow = pmap ? (size_t)((row & 63) * TSTEPS + (row >> 6))
                                         : (size_t)row;
                C[orow * ldc + col] = acc[fm][fn][r] + bb;
            }
        }
}

// ---------------------------------------------------------------------------
// Skinny bf16x3 MFMA GEMM, split-K partials.
// ---------------------------------------------------------------------------
__global__ __launch_bounds__(256) void gemm_sk(
    const float* __restrict__ A,
    const short* __restrict__ Bh16, const short* __restrict__ Bl16,
    float* __restrict__ P, int N, int K, int lda, int ldb, int Kc)
{
    __shared__ short Ah[64 * 40], Al[64 * 40];
    __shared__ short Bh[128 * 40], Bl[128 * 40];

    const int tid = threadIdx.x;
    const int n0  = blockIdx.x * 128;
    const int s   = blockIdx.z;
    const int kb  = s * Kc;

    const int lane = tid & 63;
    const int w    = tid >> 6;
    const int wn   = w * 32;
    const int lm   = lane & 15;
    const int lk   = lane >> 4;

    const int a_r = tid >> 2;
    const int a_c = (tid & 3) * 8;
    const int b_r = tid >> 1;
    const int b_c = (tid & 1) * 16;

    f32x4 acc[4][2];
#pragma unroll
    for (int i = 0; i < 4; i++)
#pragma unroll
        for (int j = 0; j < 2; j++) acc[i][j] = (f32x4)0.f;

    for (int k0 = kb; k0 < kb + Kc; k0 += 32) {
        const float* ap = A + (size_t)a_r * lda + (k0 + a_c);
        float4 q0 = *(const float4*)(ap);
        float4 q1 = *(const float4*)(ap + 4);
        float f[8] = {q0.x, q0.y, q0.z, q0.w, q1.x, q1.y, q1.z, q1.w};
        bf16x8 ah, al;
#pragma unroll
        for (int j = 0; j < 8; j++) {
            short hh, ll;
            split_bf(f[j], hh, ll); ah[j] = hh; al[j] = ll;
        }
        const short* pb = Bh16 + (size_t)(n0 + b_r) * ldb + (k0 + b_c);
        bf16x8 bh0 = *(const bf16x8*)pb, bh1 = *(const bf16x8*)(pb + 8);
        const short* qb = Bl16 + (size_t)(n0 + b_r) * ldb + (k0 + b_c);
        bf16x8 bl0 = *(const bf16x8*)qb, bl1 = *(const bf16x8*)(qb + 8);

        __syncthreads();
        *(bf16x8*)&Ah[a_r * 40 + a_c] = ah;
        *(bf16x8*)&Al[a_r * 40 + a_c] = al;
        *(bf16x8*)&Bh[b_r * 40 + b_c]     = bh0;
        *(bf16x8*)&Bh[b_r * 40 + b_c + 8] = bh1;
        *(bf16x8*)&Bl[b_r * 40 + b_c]     = bl0;
        *(bf16x8*)&Bl[b_r * 40 + b_c + 8] = bl1;
        __syncthreads();

        bf16x8 afh[4], afl[4], bfh[2], bfl[2];
#pragma unroll
        for (int fm = 0; fm < 4; fm++) {
            const int idx = (fm * 16 + lm) * 40 + lk * 8;
            afh[fm] = *(bf16x8*)&Ah[idx];
            afl[fm] = *(bf16x8*)&Al[idx];
        }
#pragma unroll
        for (int fn = 0; fn < 2; fn++) {
            const int idx = (wn + fn * 16 + lm) * 40 + lk * 8;
            bfh[fn] = *(bf16x8*)&Bh[idx];
            bfl[fn] = *(bf16x8*)&Bl[idx];
        }
#pragma unroll
        for (int fm = 0; fm < 4; fm++)
#pragma unroll
            for (int fn = 0; fn < 2; fn++) {
                acc[fm][fn] = __builtin_amdgcn_mfma_f32_16x16x32_bf16(afh[fm], bfh[fn], acc[fm][fn], 0, 0, 0);
                acc[fm][fn] = __builtin_amdgcn_mfma_f32_16x16x32_bf16(afh[fm], bfl[fn], acc[fm][fn], 0, 0, 0);
                acc[fm][fn] = __builtin_amdgcn_mfma_f32_16x16x32_bf16(afl[fm], bfh[fn], acc[fm][fn], 0, 0, 0);
            }
    }

    float* Ps = P + (size_t)s * 64 * N;
#pragma unroll
    for (int fm = 0; fm < 4; fm++)
#pragma unroll
        for (int fn = 0; fn < 2; fn++) {
            const int col = n0 + wn + fn * 16 + lm;
#pragma unroll
            for (int r = 0; r < 4; r++) {
                const int row = fm * 16 + lk * 4 + r;
                Ps[(size_t)row * N + col] = acc[fm][fn][r];
            }
        }
}

// ---------------------------------------------------------------------------
// fp32 tiled GEMM (h0/c0 init + fallback)
// ---------------------------------------------------------------------------
__global__ __launch_bounds__(256) void gemm64(
    const float* __restrict__ A, const float* __restrict__ B,
    const float* __restrict__ bias, float* __restrict__ C,
    int N, int K, int Kc, int ldc, int act, int direct)
{
    __shared__ float As[16][64];
    __shared__ float Bs[16][68];

    const int tid = threadIdx.x;
    const int n0  = blockIdx.x * 64;
    const int m0  = blockIdx.y * 64;
    const int s   = blockIdx.z;
    const int kb  = s * Kc;
    const int ke  = min(K, kb + Kc);

    const int tm = (tid >> 4) << 2;
    const int tn = (tid & 15) << 2;

    float acc[4][4];
#pragma unroll
    for (int i = 0; i < 4; i++)
#pragma unroll
        for (int j = 0; j < 4; j++) acc[i][j] = 0.f;

    const int a_m = tid >> 2;
    const int a_k = (tid & 3) << 2;
    const int b_k = tid >> 4;
    const int b_n = (tid & 15) << 2;
    const bool n4 = ((N & 3) == 0);

    for (int k0 = kb; k0 < ke; k0 += 16) {
        float4 av = *(const float4*)(A + (size_t)(m0 + a_m) * K + (k0 + a_k));
        float4 bv;
        {
            const int nn = n0 + b_n;
            const float* brow = B + (size_t)(k0 + b_k) * N;
            if (n4) {
                bv = (nn < N) ? *(const float4*)(brow + nn) : make_float4(0.f,0.f,0.f,0.f);
            } else {
                bv.x = (nn + 0 < N) ? brow[nn + 0] : 0.f;
                bv.y = (nn + 1 < N) ? brow[nn + 1] : 0.f;
                bv.z = (nn + 2 < N) ? brow[nn + 2] : 0.f;
                bv.w = (nn + 3 < N) ? brow[nn + 3] : 0.f;
            }
        }
        __syncthreads();
        As[a_k + 0][a_m] = av.x;
        As[a_k + 1][a_m] = av.y;
        As[a_k + 2][a_m] = av.z;
        As[a_k + 3][a_m] = av.w;
        *(float4*)&Bs[b_k][b_n] = bv;
        __syncthreads();
#pragma unroll
        for (int k = 0; k < 16; k++) {
            float4 a4 = *(const float4*)&As[k][tm];
            float4 b4 = *(const float4*)&Bs[k][tn];
            acc[0][0] = fmaf(a4.x, b4.x, acc[0][0]);
            acc[0][1] = fmaf(a4.x, b4.y, acc[0][1]);
            acc[0][2] = fmaf(a4.x, b4.z, acc[0][2]);
            acc[0][3] = fmaf(a4.x, b4.w, acc[0][3]);
            acc[1][0] = fmaf(a4.y, b4.x, acc[1][0]);
            acc[1][1] = fmaf(a4.y, b4.y, acc[1][1]);
            acc[1][2] = fmaf(a4.y, b4.z, acc[1][2]);
            acc[1][3] = fmaf(a4.y, b4.w, acc[1][3]);
            acc[2][0] = fmaf(a4.z, b4.x, acc[2][0]);
            acc[2][1] = fmaf(a4.z, b4.y, acc[2][1]);
            acc[2][2] = fmaf(a4.z, b4.z, acc[2][2]);
            acc[2][3] = fmaf(a4.z, b4.w, acc[2][3]);
            acc[3][0] = fmaf(a4.w, b4.x, acc[3][0]);
            acc[3][1] = fmaf(a4.w, b4.y, acc[3][1]);
            acc[3][2] = fmaf(a4.w, b4.z, acc[3][2]);
            acc[3][3] = fmaf(a4.w, b4.w, acc[3][3]);
        }
    }

    if (direct) {
#pragma unroll
        for (int i = 0; i < 4; i++) {
            const int m = m0 + tm + i;
            const size_t row = (size_t)m * ldc;
#pragma unroll
            for (int j = 0; j < 4; j++) {
                const int n = n0 + tn + j;
                if (n < N) {
                    float v = acc[i][j] + (bias ? bias[n] : 0.f);
                    if (act == 1) v = fast_tanh(v);
                    else if (act == 2) v = fast_sig(v);
                    C[row + n] = v;
                }
            }
        }
    } else {
        float* Pp = C + (size_t)s * 64 * N;
#pragma unroll
        for (int i = 0; i < 4; i++) {
#pragma unroll
            for (int j = 0; j < 4; j++) {
                const int n = n0 + tn + j;
                if (n < N) Pp[(size_t)(tm + i) * N + n] = acc[i][j];
            }
        }
    }
}

// fallback big GEMM (round-3, validated)
__global__ __launch_bounds__(256) void gemm_mfma3(
    const float* __restrict__ A, const float* __restrict__ B,
    const float* __restrict__ bias, float* __restrict__ C,
    int M, int N, int K, int lda, int ldb, int ldc, int pmap)
{
    __shared__ short Ah[128 * 40], Al[128 * 40];
    __shared__ short Bh[128 * 40], Bl[128 * 40];

    const int tid = threadIdx.x;
    const int n0  = blockIdx.x * 128;
    const int m0  = blockIdx.y * 128;

    const int lane = tid & 63;
    const int w    = tid >> 6;
    const int wm   = (w >> 1) * 64;
    const int wn   = (w & 1) * 64;
    const int lm   = lane & 15;
    const int lk   = lane >> 4;

    const int ar = tid >> 1;
    const int ac = (tid & 1) * 16;
    const int kb = (tid & 15) * 2;
    const int c8 = (tid >> 4) * 8;

    const bool bvec = ((ldb & 3) == 0) && (n0 + 128 <= N);

    f32x4 acc[4][4];
#pragma unroll
    for (int i = 0; i < 4; i++)
#pragma unroll
        for (int j = 0; j < 4; j++) acc[i][j] = (f32x4)0.f;

    for (int k0 = 0; k0 < K; k0 += 32) {
        float f[16];
        if (m0 + ar < M) {
            const float* ap = A + (size_t)(m0 + ar) * lda + (k0 + ac);
            float4 q0 = *(const float4*)(ap);
            float4 q1 = *(const float4*)(ap + 4);
            float4 q2 = *(const float4*)(ap + 8);
            float4 q3 = *(const float4*)(ap + 12);
            f[0]=q0.x; f[1]=q0.y; f[2]=q0.z; f[3]=q0.w;
            f[4]=q1.x; f[5]=q1.y; f[6]=q1.z; f[7]=q1.w;
            f[8]=q2.x; f[9]=q2.y; f[10]=q2.z; f[11]=q2.w;
            f[12]=q3.x; f[13]=q3.y; f[14]=q3.z; f[15]=q3.w;
        } else {
#pragma unroll
            for (int j = 0; j < 16; j++) f[j] = 0.f;
        }
        bf16x8 h0, h1, l0, l1;
#pragma unroll
        for (int j = 0; j < 8; j++) {
            short hh, ll;
            split_bf(f[j], hh, ll);     h0[j] = hh; l0[j] = ll;
            split_bf(f[8 + j], hh, ll); h1[j] = hh; l1[j] = ll;
        }
        float g0[8], g1[8];
        if (bvec) {
            const float* bp0 = B + (size_t)(k0 + kb) * ldb + (n0 + c8);
            const float* bp1 = bp0 + ldb;
            float4 q0 = *(const float4*)(bp0);
            float4 q1 = *(const float4*)(bp0 + 4);
            float4 q2 = *(const float4*)(bp1);
            float4 q3 = *(const float4*)(bp1 + 4);
            g0[0]=q0.x; g0[1]=q0.y; g0[2]=q0.z; g0[3]=q0.w;
            g0[4]=q1.x; g0[5]=q1.y; g0[6]=q1.z; g0[7]=q1.w;
            g1[0]=q2.x; g1[1]=q2.y; g1[2]=q2.z; g1[3]=q2.w;
            g1[4]=q3.x; g1[5]=q3.y; g1[6]=q3.z; g1[7]=q3.w;
        } else {
            const float* bp0 = B + (size_t)(k0 + kb) * ldb;
            const float* bp1 = bp0 + ldb;
#pragma unroll
            for (int j = 0; j < 8; j++) {
                const int nn = n0 + c8 + j;
                g0[j] = (nn < N) ? bp0[nn] : 0.f;
                g1[j] = (nn < N) ? bp1[nn] : 0.f;
            }
        }
        __syncthreads();
        *(bf16x8*)&Ah[ar * 40 + ac]     = h0;
        *(bf16x8*)&Ah[ar * 40 + ac + 8] = h1;
        *(bf16x8*)&Al[ar * 40 + ac]     = l0;
        *(bf16x8*)&Al[ar * 40 + ac + 8] = l1;
#pragma unroll
        for (int j = 0; j < 8; j++) {
            short ha, la, hb, lb;
            split_bf(g0[j], ha, la);
            split_bf(g1[j], hb, lb);
            const int ci = (c8 + j) * 40 + kb;
            *(int*)&Bh[ci] = (int)((unsigned short)ha | ((unsigned)(unsigned short)hb << 16));
            *(int*)&Bl[ci] = (int)((unsigned short)la | ((unsigned)(unsigned short)lb << 16));
        }
        __syncthreads();

        bf16x8 afh[4], afl[4], bfh[4], bfl[4];
#pragma unroll
        for (int fm = 0; fm < 4; fm++) {
            const int idx = (wm + fm * 16 + lm) * 40 + lk * 8;
            afh[fm] = *(bf16x8*)&Ah[idx];
            afl[fm] = *(bf16x8*)&Al[idx];
        }
#pragma unroll
        for (int fn = 0; fn < 4; fn++) {
            const int idx = (wn + fn * 16 + lm) * 40 + lk * 8;
            bfh[fn] = *(bf16x8*)&Bh[idx];
            bfl[fn] = *(bf16x8*)&Bl[idx];
        }
#pragma unroll
        for (int fm = 0; fm < 4; fm++)
#pragma unroll
            for (int fn = 0; fn < 4; fn++) {
                acc[fm][fn] = __builtin_amdgcn_mfma_f32_16x16x32_bf16(afh[fm], bfh[fn], acc[fm][fn], 0, 0, 0);
                acc[fm][fn] = __builtin_amdgcn_mfma_f32_16x16x32_bf16(afh[fm], bfl[fn], acc[fm][fn], 0, 0, 0);
                acc[fm][fn] = __builtin_amdgcn_mfma_f32_16x16x32_bf16(afl[fm], bfh[fn], acc[fm][fn], 0, 0, 0);
            }
    }

#pragma unroll
    for (int fm = 0; fm < 4; fm++) {
#pragma unroll
        for (int fn = 0; fn < 4; fn++) {
            const int col = n0 + wn + fn * 16 + lm;
            if (col >= N) continue;
            const float bb = bias ? bias[col] : 0.f;
#pragma unroll
            for (int r = 0; r < 4; r++) {
                const int row = m0 + wm + fm * 16 + lk * 4 + r;
                if (row >= M) continue;
                const size_t orow = pmap ? (size_t)((row & 63) * TSTEPS + (row >> 6))
                                         : (size_t)row;
                C[orow * ldc + col] = acc[fm][fn][r] + bb;
            }
        }
    }
}

__global__ __launch_bounds__(256) void reduce_partials(
    const float* __restrict__ P, int S, int N,
    const float* __restrict__ bias, float* __restrict__ C, int ldc, int act)
{
    const int idx = blockIdx.x * 256 + threadIdx.x;
    const int total = 64 * N;
    if (idx >= total) return;
    const int m = idx / N;
    const int n = idx - m * N;
    float v = bias ? bias[n] : 0.f;
    for (int s = 0; s < S; s++) v += P[(size_t)s * total + idx];
    if (act == 1) v = fast_tanh(v);
    else if (act == 2) v = fast_sig(v);
    else if (act == 3 && n >= RNND) v = fast_sig(v);
    C[(size_t)m * ldc + n] = v;
}

__global__ __launch_bounds__(256) void reduce_lstm(
    const float* __restrict__ P, int S, const float* __restrict__ bsum,
    float* __restrict__ hn, float* __restrict__ c,
    short* __restrict__ hbh, short* __restrict__ hbl)
{
    const int idx = blockIdx.x * 256 + threadIdx.x;
    const int b = idx >> 10, r = idx & 1023;
    const float* pb = P + (size_t)b * 4096;
    float gi = bsum[r], gf = bsum[1024 + r], gg = bsum[2048 + r], go = bsum[3072 + r];
    for (int s = 0; s < S; s++) {
        const float* q = pb + (size_t)s * 64 * 4096;
        gi += q[r]; gf += q[1024 + r]; gg += q[2048 + r]; go += q[3072 + r];
    }
    const float ig = fast_sig(gi);
    const float fg = fast_sig(gf);
    const float g2 = fast_tanh(gg);
    const float og = fast_sig(go);
    const float cn = fg * c[idx] + ig * g2;
    const float hv = og * fast_tanh(cn);
    c[idx]  = cn;
    hn[idx] = hv;
    if (hbh) {
        short hi, lo;
        split_bf(hv, hi, lo);
        hbh[idx] = hi;
        hbl[idx] = lo;
    }
}

__global__ __launch_bounds__(256) void mean_img(
    const float* __restrict__ img, float* __restrict__ avg)
{
    const int b = blockIdx.x;
    const int d = blockIdx.y * 256 + threadIdx.x;
    const float* p = img + (size_t)b * LIMG * DIMG + d;
    float s = 0.f;
    for (int l = 0; l < LIMG; l++) s += p[(size_t)l * DIMG];
    avg[(size_t)b * DIMG + d] = s * (1.f / 196.f);
}

__global__ __launch_bounds__(256) void concat_w(
    const float* __restrict__ WU, const float* __restrict__ Wfb,
    float* __restrict__ Wug)
{
    const int idx = blockIdx.x * 256 + threadIdx.x;
    if (idx >= 1024 * 3072) return;
    const int k = idx / 3072;
    const int j = idx - k * 3072;
    Wug[idx] = (j < 1024) ? WU[(size_t)k * 1024 + j] : Wfb[(size_t)k * 2048 + (j - 1024)];
}

__global__ __launch_bounds__(256) void concat_b(
    const float* __restrict__ bU, const float* __restrict__ bfb,
    const float* __restrict__ bih, const float* __restrict__ bhh,
    float* __restrict__ bug, float* __restrict__ bsum)
{
    const int j = blockIdx.x * 256 + threadIdx.x;
    if (j < 3072) bug[j] = (j < 1024) ? bU[j] : bfb[j - 1024];
    if (j < 4096) bsum[j] = bih[j] + bhh[j];
}

__global__ __launch_bounds__(256) void attn_e(
    const float* __restrict__ Ws, const float* __restrict__ ug,
    const float* __restrict__ Wv, const float* __restrict__ bv,
    float* __restrict__ e)
{
    const int wv   = (blockIdx.x << 2) + (threadIdx.x >> 6);
    const int lane = threadIdx.x & 63;
    const int b    = wv / LIMG;
    const float* wrow = Ws + (size_t)wv * RNND;
    const float* urow = ug + (size_t)b * 3072;
    float acc = 0.f;
#pragma unroll
    for (int k = lane * 4; k < RNND; k += 256) {
        float4 wq = *(const float4*)(wrow + k);
        float4 uq = *(const float4*)(urow + k);
        float4 vq = *(const float4*)(Wv + k);
        acc += fast_tanh(wq.x + uq.x) * vq.x + fast_tanh(wq.y + uq.y) * vq.y
             + fast_tanh(wq.z + uq.z) * vq.z + fast_tanh(wq.w + uq.w) * vq.w;
    }
#pragma unroll
    for (int off = 32; off > 0; off >>= 1) acc += __shfl_down(acc, off);
    if (lane == 0) e[wv] = acc + bv[0];
}

// ---------------------------------------------------------------------------
// Fused softmax + alphas write + x assembly.
// grid (64, 5): y==0 handles emb/h/alphas; y in 1..4 handles 512-wide ctx.
// ---------------------------------------------------------------------------
__global__ __launch_bounds__(256) void ctx_fuse(
    const float* __restrict__ e, const float* __restrict__ img,
    const float* __restrict__ ug, const float* __restrict__ embt,
    const int* __restrict__ captions, const float* __restrict__ h,
    float* __restrict__ x, float* __restrict__ alphas_out, int t)
{
    __shared__ float al[256];
    __shared__ float red[256];
    const int b = blockIdx.x, y = blockIdx.y, tid = threadIdx.x;

    const float v = (tid < LIMG) ? e[b * LIMG + tid] : -3.0e38f;
    red[tid] = v; __syncthreads();
    for (int s = 128; s > 0; s >>= 1) {
        if (tid < s) red[tid] = fmaxf(red[tid], red[tid + s]);
        __syncthreads();
    }
    const float mx = red[0]; __syncthreads();
    const float ex = (tid < LIMG) ? __expf(v - mx) : 0.f;
    red[tid] = ex; __syncthreads();
    for (int s = 128; s > 0; s >>= 1) {
        if (tid < s) red[tid] += red[tid + s];
        __syncthreads();
    }
    const float inv = 1.f / red[0];
    al[tid] = ex * inv;
    __syncthreads();

    if (y == 0) {
        if (tid < LIMG)
            alphas_out[(size_t)b * (TSTEPS * LIMG) + t * LIMG + tid] = al[tid];
        const int tok = (t == 0) ? 10001 : captions[b * 16 + (t - 1)];
        for (int j = tid; j < EMBD; j += 256)
            x[(size_t)b * 3584 + j] = embt[(size_t)tok * EMBD + j];
        for (int j = tid; j < RNND; j += 256)
            x[(size_t)b * 3584 + 2560 + j] = h[(size_t)b * RNND + j];
    } else {
        const int d0 = (y - 1) * 512 + tid * 2;
        const float* ib = img + (size_t)b * LIMG * DIMG + d0;
        float a0 = 0.f, a1 = 0.f;
#pragma unroll 4
        for (int l = 0; l < LIMG; l++) {
            float2 q = *(const float2*)(ib + (size_t)l * DIMG);
            a0 = fmaf(al[l], q.x, a0);
            a1 = fmaf(al[l], q.y, a1);
        }
        const float g0 = ug[(size_t)b * 3072 + 1024 + d0];
        const float g1 = ug[(size_t)b * 3072 + 1024 + d0 + 1];
        x[(size_t)b * 3584 + EMBD + d0]     = g0 * a0;
        x[(size_t)b * 3584 + EMBD + d0 + 1] = g1 * a1;
    }
}

__global__ __launch_bounds__(256) void softmax_alpha(
    const float* __restrict__ e, float* __restrict__ alpha,
    float* __restrict__ alphas_out, int t)
{
    __shared__ float red[256];
    const int b = blockIdx.x, tid = threadIdx.x;
    const float v = (tid < LIMG) ? e[b * LIMG + tid] : -3.0e38f;
    red[tid] = v; __syncthreads();
    for (int s = 128; s > 0; s >>= 1) {
        if (tid < s) red[tid] = fmaxf(red[tid], red[tid + s]);
        __syncthreads();
    }
    const float mx = red[0]; __syncthreads();
    const float ex = (tid < LIMG) ? __expf(v - mx) : 0.f;
    red[tid] = ex; __syncthreads();
    for (int s = 128; s > 0; s >>= 1) {
        if (tid < s) red[tid] += red[tid + s];
        __syncthreads();
    }
    const float inv = 1.f / red[0];
    if (tid < LIMG) {
        const float a = ex * inv;
        alpha[b * LIMG + tid] = a;
        alphas_out[(size_t)b * (TSTEPS * LIMG) + t * LIMG + tid] = a;
    }
}

__global__ __launch_bounds__(128) void assemble_x(
    const float* __restrict__ img, const float* __restrict__ alpha,
    const float* __restrict__ ug, const float* __restrict__ emb,
    const int* __restrict__ captions, const float* __restrict__ h,
    float* __restrict__ x, int t, int stride)
{
    const int b = blockIdx.x, y = blockIdx.y, tid = threadIdx.x;
    if (y < 4) {
        const int tok = (t == 0) ? 10001 : captions[b * 16 + (t - 1)];
        const int j = y * 128 + tid;
        x[(size_t)b * stride + j] = emb[(size_t)tok * EMBD + j];
    } else if (y < 20) {
        __shared__ float al[LIMG];
        for (int i = tid; i < LIMG; i += 128) al[i] = alpha[b * LIMG + i];
        __syncthreads();
        const int d = (y - 4) * 128 + tid;
        const float* ib = img + (size_t)b * LIMG * DIMG + d;
        float accv = 0.f;
#pragma unroll 4
        for (int l = 0; l < LIMG; l++) accv = fmaf(al[l], ib[(size_t)l * DIMG], accv);
        const float g = ug[(size_t)b * 3072 + 1024 + d];
        x[(size_t)b * stride + EMBD + d] = g * accv;
    } else {
        const int j = (y - 20) * 128 + tid;
        x[(size_t)b * stride + 2560 + j] = h[(size_t)b * RNND + j];
    }
}

extern "C" void kernel_launch(void* const* d_in, const int* in_sizes, int n_in,
                              void* d_out, int out_size, void* d_ws, size_t ws_size,
                              hipStream_t stream)
{
    const float* img      = (const float*)d_in[0];
    const int*   captions = (const int*)d_in[1];
    const float* emb      = (const float*)d_in[2];
    const float* Wih      = (const float*)d_in[3];
    const float* Whh      = (const float*)d_in[4];
    const float* bih      = (const float*)d_in[5];
    const float* bhh      = (const float*)d_in[6];
    const float* Wh0      = (const float*)d_in[7];
    const float* bh0      = (const float*)d_in[8];
    const float* Wc0      = (const float*)d_in[9];
    const float* bc0      = (const float*)d_in[10];
    const float* Wfb      = (const float*)d_in[11];
    const float* bfb      = (const float*)d_in[12];
    const float* Wout     = (const float*)d_in[13];
    const float* bout     = (const float*)d_in[14];
    const float* WU       = (const float*)d_in[15];
    const float* bU       = (const float*)d_in[16];
    const float* WW       = (const float*)d_in[17];
    const float* bW       = (const float*)d_in[18];
    const float* Wv       = (const float*)d_in[19];
    const float* bv       = (const float*)d_in[20];

    float* preds      = (float*)d_out;
    float* alphas_out = preds + (size_t)NB * TSTEPS * VOUTD;

    const size_t NEED = 190000000;

    if (ws_size >= NEED) {
        float* w = (float*)d_ws;
        float* Ws    = w; w += (size_t)12544 * 1024;
        float* ug    = w; w += (size_t)64 * 3072;
        float* P     = w; w += (size_t)8 * 64 * 4096;
        float* e     = w; w += (size_t)64 * LIMG;
        float* alpha = w; w += (size_t)64 * LIMG;
        float* xh    = w; w += (size_t)64 * 3584;
        float* h     = w; w += (size_t)64 * RNND;
        float* c     = w; w += (size_t)64 * RNND;
        float* avg   = w; w += (size_t)64 * DIMG;
        float* bsum  = w; w += 4096;
        float* bug   = w; w += 3072;
        short* u = (short*)w;
        short* Hbh     = u; u += (size_t)1280 * 1024;
        short* Hbl     = u; u += (size_t)1280 * 1024;
        short* WWTh    = u; u += (size_t)1024 * 2048;
        short* WWTl    = u; u += (size_t)1024 * 2048;
        short* WugTh   = u; u += (size_t)3072 * 1024;
        short* WugTl   = u; u += (size_t)3072 * 1024;
        short* WfullTh = u; u += (size_t)4096 * 3584;
        short* WfullTl = u; u += (size_t)4096 * 3584;
        short* WoutTh  = u; u += (size_t)10112 * 1024;
        short* WoutTl  = u; u += (size_t)10112 * 1024;

        mean_img<<<dim3(NB, 8), 256, 0, stream>>>(img, avg);
        gemm64<<<dim3(16, 1, 8), 256, 0, stream>>>(avg, Wh0, nullptr, P, 1024, 2048, 256, 0, 0, 0);
        reduce_partials<<<256, 256, 0, stream>>>(P, 8, 1024, bh0, h, 1024, 1);
        gemm64<<<dim3(16, 1, 8), 256, 0, stream>>>(avg, Wc0, nullptr, P, 1024, 2048, 256, 0, 0, 0);
        reduce_partials<<<256, 256, 0, stream>>>(P, 8, 1024, bc0, c, 1024, 1);
        concat_b<<<16, 256, 0, stream>>>(bU, bfb, bih, bhh, bug, bsum);

        tsplit<<<dim3(32, 16), 256, 0, stream>>>(WW, 1024, WW, 1024, WWTh, WWTl, 1024, 2048, 2048, 0);
        tsplit<<<dim3(16, 48), 256, 0, stream>>>(WU, 1024, Wfb, 2048, WugTh, WugTl, 3072, 1024, 1024, 1024);
        tsplit<<<dim3(56, 64), 256, 0, stream>>>(Wih, 4096, Whh, 4096, WfullTh, WfullTl, 4096, 3584, 2560, 0);
        tsplit<<<dim3(16, 157), 256, 0, stream>>>(Wout, VOUTD, Wout, VOUTD, WoutTh, WoutTl, VOUTD, 1024, 1024, 0);

        // W_s = img @ WW + bW : 64x128 tiles, grid (8, 196)
        gemm_mt<<<dim3(8, 196), 256, 0, stream>>>(img, nullptr, nullptr, WWTh, WWTl,
                                                  bW, Ws, 1024, 2048, 2048, 2048, 1024, 0);

        for (int t = 0; t < TSTEPS; t++) {
            gemm_sk<<<dim3(24, 1, 8), 256, 0, stream>>>(h, WugTh, WugTl, P, 3072, 1024, 1024, 1024, 128);
            reduce_partials<<<768, 256, 0, stream>>>(P, 8, 3072, bug, ug, 3072, 3);
            attn_e<<<3136, 256, 0, stream>>>(Ws, ug, Wv, bv, e);
            ctx_fuse<<<dim3(NB, 5), 256, 0, stream>>>(e, img, ug, emb, captions, h, xh, alphas_out, t);
            gemm_sk<<<dim3(32, 1, 7), 256, 0, stream>>>(xh, WfullTh, WfullTl, P, 4096, 3584, 3584, 3584, 512);
            reduce_lstm<<<256, 256, 0, stream>>>(P, 7, bsum, h, c,
                                                 Hbh + (size_t)(t + 1) * 65536,
                                                 Hbl + (size_t)(t + 1) * 65536);
        }

        // preds: 64x128 tiles, grid (79, 17), pmap output
        gemm_mt<<<dim3(79, 17), 256, 0, stream>>>(nullptr, Hbh + 65536, Hbl + 65536,
                                                  WoutTh, WoutTl, bout, preds,
                                                  VOUTD, 1024, 1024, 1024, VOUTD, 1);
    } else {
        float* w = (float*)d_ws;
        float* Ws    = w; w += (size_t)12544 * 1024;
        float* ug    = w; w += (size_t)64 * 3072;
        float* P     = w; w += (size_t)12 * 64 * 4096;
        float* e     = w; w += (size_t)64 * LIMG;
        float* alpha = w; w += (size_t)64 * LIMG;
        float* x     = w; w += (size_t)64 * 2560;
        float* Hh    = w; w += (size_t)18 * 64 * RNND;
        float* c     = w; w += (size_t)64 * RNND;
        float* avg   = w; w += (size_t)64 * DIMG;
        float* bsum  = w; w += 4096;
        float* Wug   = w; w += (size_t)1024 * 3072;
        float* bug   = w; w += 3072;

        mean_img<<<dim3(NB, 8), 256, 0, stream>>>(img, avg);
        gemm64<<<dim3(16, 1, 8), 256, 0, stream>>>(avg, Wh0, nullptr, P, 1024, 2048, 256, 0, 0, 0);
        reduce_partials<<<256, 256, 0, stream>>>(P, 8, 1024, bh0, Hh, 1024, 1);
        gemm64<<<dim3(16, 1, 8), 256, 0, stream>>>(avg, Wc0, nullptr, P, 1024, 2048, 256, 0, 0, 0);
        reduce_partials<<<256, 256, 0, stream>>>(P, 8, 1024, bc0, c, 1024, 1);
        concat_b<<<16, 256, 0, stream>>>(bU, bfb, bih, bhh, bug, bsum);
        concat_w<<<12288, 256, 0, stream>>>(WU, Wfb, Wug);
        gemm_mfma3<<<dim3(8, 98), 256, 0, stream>>>(img, WW, bW, Ws,
                                                    12544, 1024, 2048, 2048, 1024, 1024, 0);
        for (int t = 0; t < TSTEPS; t++) {
            const float* hc = Hh + (size_t)t * 64 * RNND;
            float*       hn = Hh + (size_t)(t + 1) * 64 * RNND;
            gemm64<<<dim3(48, 1, 8), 256, 0, stream>>>(hc, Wug, nullptr, P, 3072, 1024, 128, 0, 0, 0);
            reduce_partials<<<768, 256, 0, stream>>>(P, 8, 3072, bug, ug, 3072, 3);
            attn_e<<<3136, 256, 0, stream>>>(Ws, ug, Wv, bv, e);
            softmax_alpha<<<NB, 256, 0, stream>>>(e, alpha, alphas_out, t);
            assemble_x<<<dim3(NB, 20), 128, 0, stream>>>(img, alpha, ug, emb, captions, hc, x, t, 2560);
            gemm64<<<dim3(64, 1, 8), 256, 0, stream>>>(x, Wih, nullptr, P, 4096, 2560, 320, 0, 0, 0);
            gemm64<<<dim3(64, 1, 4), 256, 0, stream>>>(hc, Whh, nullptr, P + (size_t)8 * 64 * 4096,
                                                       4096, 1024, 256, 0, 0, 0);
            reduce_lstm<<<256, 256, 0, stream>>>(P, 12, bsum, hn, c, nullptr, nullptr);
        }
        gemm_mfma3<<<dim3(79, 9), 256, 0, stream>>>(Hh + (size_t)64 * RNND, Wout, bout, preds,
                                                    TSTEPS * 64, VOUTD, 1024, 1024, VOUTD, VOUTD, 1);
    }
}

// Round 13
// 1788.899 us; speedup vs baseline: 1.2647x; 1.0636x over previous
//
#include <hip/hip_runtime.h>
#include <cstdint>

#define NB    64
#define LIMG  196
#define DIMG  2048
#define RNND  1024
#define EMBD  512
#define TSTEPS 17
#define VOUTD 10003

typedef short bf16x8 __attribute__((ext_vector_type(8)));
typedef float f32x4  __attribute__((ext_vector_type(4)));

__device__ __forceinline__ float fast_sig(float x) {
    return 1.f / (1.f + __expf(-x));
}
__device__ __forceinline__ float fast_tanh(float x) {
    float ax = fabsf(x);
    float e  = __expf(2.f * ax);
    float r  = 1.f - 2.f / (e + 1.f);
    return copysignf(r, x);
}
__device__ __forceinline__ void split_bf(float x, short& hi, short& lo) {
    unsigned u  = __float_as_uint(x);
    unsigned hb = u & 0xffff0000u;
    hi = (short)(u >> 16);
    float r = x - __uint_as_float(hb);
    lo = (short)(__float_as_uint(r) >> 16);
}

// ---------------------------------------------------------------------------
// Transpose + bf16 hi/lo split of weights
// ---------------------------------------------------------------------------
__global__ __launch_bounds__(256) void tsplit(
    const float* __restrict__ S1, int ld1,
    const float* __restrict__ S2, int ld2,
    short* __restrict__ outh, short* __restrict__ outl,
    int N, int K, int ksplit, int nsplit)
{
    __shared__ float T[64][65];
    const int k0 = blockIdx.x * 64, n0 = blockIdx.y * 64;
    const int tid = threadIdx.x;
    const int rr = tid >> 2;
    const int cc = (tid & 3) * 16;
    const int kk = k0 + rr;
    const int nn = n0 + cc;
    const float* rp; int col;
    if (nsplit > 0) {
        if (nn >= nsplit) { rp = S2 + (size_t)kk * ld2; col = nn - nsplit; }
        else              { rp = S1 + (size_t)kk * ld1; col = nn; }
    } else {
        if (kk < ksplit)  { rp = S1 + (size_t)kk * ld1; col = nn; }
        else              { rp = S2 + (size_t)(kk - ksplit) * ld2; col = nn; }
    }
#pragma unroll
    for (int j = 0; j < 16; j++)
        T[rr][cc + j] = (nn + j < N) ? rp[col + j] : 0.f;
    __syncthreads();
    const int wn = tid >> 2;
    const int wk = (tid & 3) * 16;
    const int gn = n0 + wn;
    if (gn >= N) return;
    bf16x8 h0, h1, l0, l1;
#pragma unroll
    for (int j = 0; j < 8; j++) {
        short hh, ll;
        split_bf(T[wk + j][wn], hh, ll);     h0[j] = hh; l0[j] = ll;
        split_bf(T[wk + 8 + j][wn], hh, ll); h1[j] = hh; l1[j] = ll;
    }
    const size_t o = (size_t)gn * K + k0 + wk;
    *(bf16x8*)&outh[o]     = h0;
    *(bf16x8*)&outh[o + 8] = h1;
    *(bf16x8*)&outl[o]     = l0;
    *(bf16x8*)&outl[o + 8] = l1;
}

// ---------------------------------------------------------------------------
// m-tiled 64x128 bf16x3 MFMA GEMM. grid (N/128 ceil, M/64).
// ---------------------------------------------------------------------------
__global__ __launch_bounds__(256) void gemm_mt(
    const float* __restrict__ Af,
    const short* __restrict__ Ah16, const short* __restrict__ Al16,
    const short* __restrict__ Bh16, const short* __restrict__ Bl16,
    const float* __restrict__ bias, float* __restrict__ C,
    int N, int K, int lda, int ldb, int ldc, int pmap)
{
    __shared__ short Ah[64 * 40], Al[64 * 40];
    __shared__ short Bh[128 * 40], Bl[128 * 40];

    const int tid = threadIdx.x;
    const int n0  = blockIdx.x * 128;
    const int m0  = blockIdx.y * 64;

    const int lane = tid & 63;
    const int w    = tid >> 6;
    const int wn   = w * 32;
    const int lm   = lane & 15;
    const int lk   = lane >> 4;

    const int a_r = tid >> 2;
    const int a_c = (tid & 3) * 8;
    const int b_r = tid >> 1;
    const int b_c = (tid & 1) * 16;

    f32x4 acc[4][2];
#pragma unroll
    for (int i = 0; i < 4; i++)
#pragma unroll
        for (int j = 0; j < 2; j++) acc[i][j] = (f32x4)0.f;

    bf16x8 rah, ral, rbh0, rbh1, rbl0, rbl1;
    auto load_tile = [&](int k0) {
        if (Af) {
            const float* ap = Af + (size_t)(m0 + a_r) * lda + (k0 + a_c);
            float4 q0 = *(const float4*)(ap);
            float4 q1 = *(const float4*)(ap + 4);
            float f[8] = {q0.x, q0.y, q0.z, q0.w, q1.x, q1.y, q1.z, q1.w};
#pragma unroll
            for (int j = 0; j < 8; j++) {
                short hh, ll;
                split_bf(f[j], hh, ll); rah[j] = hh; ral[j] = ll;
            }
        } else {
            rah = *(const bf16x8*)(Ah16 + (size_t)(m0 + a_r) * lda + (k0 + a_c));
            ral = *(const bf16x8*)(Al16 + (size_t)(m0 + a_r) * lda + (k0 + a_c));
        }
        const short* pb = Bh16 + (size_t)(n0 + b_r) * ldb + (k0 + b_c);
        rbh0 = *(const bf16x8*)pb; rbh1 = *(const bf16x8*)(pb + 8);
        const short* qb = Bl16 + (size_t)(n0 + b_r) * ldb + (k0 + b_c);
        rbl0 = *(const bf16x8*)qb; rbl1 = *(const bf16x8*)(qb + 8);
    };

    load_tile(0);
    for (int k0 = 0; k0 < K; k0 += 32) {
        __syncthreads();
        *(bf16x8*)&Ah[a_r * 40 + a_c] = rah;
        *(bf16x8*)&Al[a_r * 40 + a_c] = ral;
        *(bf16x8*)&Bh[b_r * 40 + b_c]     = rbh0;
        *(bf16x8*)&Bh[b_r * 40 + b_c + 8] = rbh1;
        *(bf16x8*)&Bl[b_r * 40 + b_c]     = rbl0;
        *(bf16x8*)&Bl[b_r * 40 + b_c + 8] = rbl1;
        __syncthreads();
        if (k0 + 32 < K) load_tile(k0 + 32);   // prefetch hides under MFMAs

        bf16x8 afh[4], afl[4], bfh[2], bfl[2];
#pragma unroll
        for (int fm = 0; fm < 4; fm++) {
            const int idx = (fm * 16 + lm) * 40 + lk * 8;
            afh[fm] = *(bf16x8*)&Ah[idx];
            afl[fm] = *(bf16x8*)&Al[idx];
        }
#pragma unroll
        for (int fn = 0; fn < 2; fn++) {
            const int idx = (wn + fn * 16 + lm) * 40 + lk * 8;
            bfh[fn] = *(bf16x8*)&Bh[idx];
            bfl[fn] = *(bf16x8*)&Bl[idx];
        }
#pragma unroll
        for (int fm = 0; fm < 4; fm++)
#pragma unroll
            for (int fn = 0; fn < 2; fn++) {
                acc[fm][fn] = __builtin_amdgcn_mfma_f32_16x16x32_bf16(afh[fm], bfh[fn], acc[fm][fn], 0, 0, 0);
                acc[fm][fn] = __builtin_amdgcn_mfma_f32_16x16x32_bf16(afh[fm], bfl[fn], acc[fm][fn], 0, 0, 0);
                acc[fm][fn] = __builtin_amdgcn_mfma_f32_16x16x32_bf16(afl[fm], bfh[fn], acc[fm][fn], 0, 0, 0);
            }
    }

#pragma unroll
    for (int fm = 0; fm < 4; fm++)
#pragma unroll
        for (int fn = 0; fn < 2; fn++) {
            const int col = n0 + wn + fn * 16 + lm;
            if (col >= N) continue;
            const float bb = bias ? bias[col] : 0.f;
#pragma unroll
            for (int r = 0; r < 4; r++) {
                const int row = m0 + fm * 16 + lk * 4 + r;
                const size_t orow = pmap ? (size_t)((row & 63) * TSTEPS + (row >> 6))
                                         : (size_t)row;
                C[orow * ldc + col] = acc[fm][fn][r] + bb;
            }
        }
}

// ---------------------------------------------------------------------------
// Skinny bf16x3 MFMA GEMM, split-K partials.
// ---------------------------------------------------------------------------
__global__ __launch_bounds__(256) void gemm_sk(
    const float* __restrict__ A,
    const short* __restrict__ Bh16, const short* __restrict__ Bl16,
    float* __restrict__ P, int N, int K, int lda, int ldb, int Kc)
{
    __shared__ short Ah[64 * 40], Al[64 * 40];
    __shared__ short Bh[128 * 40], Bl[128 * 40];

    const int tid = threadIdx.x;
    const int n0  = blockIdx.x * 128;
    const int s   = blockIdx.z;
    const int kb  = s * Kc;

    const int lane = tid & 63;
    const int w    = tid >> 6;
    const int wn   = w * 32;
    const int lm   = lane & 15;
    const int lk   = lane >> 4;

    const int a_r = tid >> 2;
    const int a_c = (tid & 3) * 8;
    const int b_r = tid >> 1;
    const int b_c = (tid & 1) * 16;

    f32x4 acc[4][2];
#pragma unroll
    for (int i = 0; i < 4; i++)
#pragma unroll
        for (int j = 0; j < 2; j++) acc[i][j] = (f32x4)0.f;

    for (int k0 = kb; k0 < kb + Kc; k0 += 32) {
        const float* ap = A + (size_t)a_r * lda + (k0 + a_c);
        float4 q0 = *(const float4*)(ap);
        float4 q1 = *(const float4*)(ap + 4);
        float f[8] = {q0.x, q0.y, q0.z, q0.w, q1.x, q1.y, q1.z, q1.w};
        bf16x8 ah, al;
#pragma unroll
        for (int j = 0; j < 8; j++) {
            short hh, ll;
            split_bf(f[j], hh, ll); ah[j] = hh; al[j] = ll;
        }
        const short* pb = Bh16 + (size_t)(n0 + b_r) * ldb + (k0 + b_c);
        bf16x8 bh0 = *(const bf16x8*)pb, bh1 = *(const bf16x8*)(pb + 8);
        const short* qb = Bl16 + (size_t)(n0 + b_r) * ldb + (k0 + b_c);
        bf16x8 bl0 = *(const bf16x8*)qb, bl1 = *(const bf16x8*)(qb + 8);

        __syncthreads();
        *(bf16x8*)&Ah[a_r * 40 + a_c] = ah;
        *(bf16x8*)&Al[a_r * 40 + a_c] = al;
        *(bf16x8*)&Bh[b_r * 40 + b_c]     = bh0;
        *(bf16x8*)&Bh[b_r * 40 + b_c + 8] = bh1;
        *(bf16x8*)&Bl[b_r * 40 + b_c]     = bl0;
        *(bf16x8*)&Bl[b_r * 40 + b_c + 8] = bl1;
        __syncthreads();

        bf16x8 afh[4], afl[4], bfh[2], bfl[2];
#pragma unroll
        for (int fm = 0; fm < 4; fm++) {
            const int idx = (fm * 16 + lm) * 40 + lk * 8;
            afh[fm] = *(bf16x8*)&Ah[idx];
            afl[fm] = *(bf16x8*)&Al[idx];
        }
#pragma unroll
        for (int fn = 0; fn < 2; fn++) {
            const int idx = (wn + fn * 16 + lm) * 40 + lk * 8;
            bfh[fn] = *(bf16x8*)&Bh[idx];
            bfl[fn] = *(bf16x8*)&Bl[idx];
        }
#pragma unroll
        for (int fm = 0; fm < 4; fm++)
#pragma unroll
            for (int fn = 0; fn < 2; fn++) {
                acc[fm][fn] = __builtin_amdgcn_mfma_f32_16x16x32_bf16(afh[fm], bfh[fn], acc[fm][fn], 0, 0, 0);
                acc[fm][fn] = __builtin_amdgcn_mfma_f32_16x16x32_bf16(afh[fm], bfl[fn], acc[fm][fn], 0, 0, 0);
                acc[fm][fn] = __builtin_amdgcn_mfma_f32_16x16x32_bf16(afl[fm], bfh[fn], acc[fm][fn], 0, 0, 0);
            }
    }

    float* Ps = P + (size_t)s * 64 * N;
#pragma unroll
    for (int fm = 0; fm < 4; fm++)
#pragma unroll
        for (int fn = 0; fn < 2; fn++) {
            const int col = n0 + wn + fn * 16 + lm;
#pragma unroll
            for (int r = 0; r < 4; r++) {
                const int row = fm * 16 + lk * 4 + r;
                Ps[(size_t)row * N + col] = acc[fm][fn][r];
            }
        }
}

// ---------------------------------------------------------------------------
// fp32 tiled GEMM (h0/c0 init + fallback)
// ---------------------------------------------------------------------------
__global__ __launch_bounds__(256) void gemm64(
    const float* __restrict__ A, const float* __restrict__ B,
    const float* __restrict__ bias, float* __restrict__ C,
    int N, int K, int Kc, int ldc, int act, int direct)
{
    __shared__ float As[16][64];
    __shared__ float Bs[16][68];

    const int tid = threadIdx.x;
    const int n0  = blockIdx.x * 64;
    const int m0  = blockIdx.y * 64;
    const int s   = blockIdx.z;
    const int kb  = s * Kc;
    const int ke  = min(K, kb + Kc);

    const int tm = (tid >> 4) << 2;
    const int tn = (tid & 15) << 2;

    float acc[4][4];
#pragma unroll
    for (int i = 0; i < 4; i++)
#pragma unroll
        for (int j = 0; j < 4; j++) acc[i][j] = 0.f;

    const int a_m = tid >> 2;
    const int a_k = (tid & 3) << 2;
    const int b_k = tid >> 4;
    const int b_n = (tid & 15) << 2;
    const bool n4 = ((N & 3) == 0);

    for (int k0 = kb; k0 < ke; k0 += 16) {
        float4 av = *(const float4*)(A + (size_t)(m0 + a_m) * K + (k0 + a_k));
        float4 bv;
        {
            const int nn = n0 + b_n;
            const float* brow = B + (size_t)(k0 + b_k) * N;
            if (n4) {
                bv = (nn < N) ? *(const float4*)(brow + nn) : make_float4(0.f,0.f,0.f,0.f);
            } else {
                bv.x = (nn + 0 < N) ? brow[nn + 0] : 0.f;
                bv.y = (nn + 1 < N) ? brow[nn + 1] : 0.f;
                bv.z = (nn + 2 < N) ? brow[nn + 2] : 0.f;
                bv.w = (nn + 3 < N) ? brow[nn + 3] : 0.f;
            }
        }
        __syncthreads();
        As[a_k + 0][a_m] = av.x;
        As[a_k + 1][a_m] = av.y;
        As[a_k + 2][a_m] = av.z;
        As[a_k + 3][a_m] = av.w;
        *(float4*)&Bs[b_k][b_n] = bv;
        __syncthreads();
#pragma unroll
        for (int k = 0; k < 16; k++) {
            float4 a4 = *(const float4*)&As[k][tm];
            float4 b4 = *(const float4*)&Bs[k][tn];
            acc[0][0] = fmaf(a4.x, b4.x, acc[0][0]);
            acc[0][1] = fmaf(a4.x, b4.y, acc[0][1]);
            acc[0][2] = fmaf(a4.x, b4.z, acc[0][2]);
            acc[0][3] = fmaf(a4.x, b4.w, acc[0][3]);
            acc[1][0] = fmaf(a4.y, b4.x, acc[1][0]);
            acc[1][1] = fmaf(a4.y, b4.y, acc[1][1]);
            acc[1][2] = fmaf(a4.y, b4.z, acc[1][2]);
            acc[1][3] = fmaf(a4.y, b4.w, acc[1][3]);
            acc[2][0] = fmaf(a4.z, b4.x, acc[2][0]);
            acc[2][1] = fmaf(a4.z, b4.y, acc[2][1]);
            acc[2][2] = fmaf(a4.z, b4.z, acc[2][2]);
            acc[2][3] = fmaf(a4.z, b4.w, acc[2][3]);
            acc[3][0] = fmaf(a4.w, b4.x, acc[3][0]);
            acc[3][1] = fmaf(a4.w, b4.y, acc[3][1]);
            acc[3][2] = fmaf(a4.w, b4.z, acc[3][2]);
            acc[3][3] = fmaf(a4.w, b4.w, acc[3][3]);
        }
    }

    if (direct) {
#pragma unroll
        for (int i = 0; i < 4; i++) {
            const int m = m0 + tm + i;
            const size_t row = (size_t)m * ldc;
#pragma unroll
            for (int j = 0; j < 4; j++) {
                const int n = n0 + tn + j;
                if (n < N) {
                    float v = acc[i][j] + (bias ? bias[n] : 0.f);
                    if (act == 1) v = fast_tanh(v);
                    else if (act == 2) v = fast_sig(v);
                    C[row + n] = v;
                }
            }
        }
    } else {
        float* Pp = C + (size_t)s * 64 * N;
#pragma unroll
        for (int i = 0; i < 4; i++) {
#pragma unroll
            for (int j = 0; j < 4; j++) {
                const int n = n0 + tn + j;
                if (n < N) Pp[(size_t)(tm + i) * N + n] = acc[i][j];
            }
        }
    }
}

// fallback big GEMM (round-3, validated)
__global__ __launch_bounds__(256) void gemm_mfma3(
    const float* __restrict__ A, const float* __restrict__ B,
    const float* __restrict__ bias, float* __restrict__ C,
    int M, int N, int K, int lda, int ldb, int ldc, int pmap)
{
    __shared__ short Ah[128 * 40], Al[128 * 40];
    __shared__ short Bh[128 * 40], Bl[128 * 40];

    const int tid = threadIdx.x;
    const int n0  = blockIdx.x * 128;
    const int m0  = blockIdx.y * 128;

    const int lane = tid & 63;
    const int w    = tid >> 6;
    const int wm   = (w >> 1) * 64;
    const int wn   = (w & 1) * 64;
    const int lm   = lane & 15;
    const int lk   = lane >> 4;

    const int ar = tid >> 1;
    const int ac = (tid & 1) * 16;
    const int kb = (tid & 15) * 2;
    const int c8 = (tid >> 4) * 8;

    const bool bvec = ((ldb & 3) == 0) && (n0 + 128 <= N);

    f32x4 acc[4][4];
#pragma unroll
    for (int i = 0; i < 4; i++)
#pragma unroll
        for (int j = 0; j < 4; j++) acc[i][j] = (f32x4)0.f;

    for (int k0 = 0; k0 < K; k0 += 32) {
        float f[16];
        if (m0 + ar < M) {
            const float* ap = A + (size_t)(m0 + ar) * lda + (k0 + ac);
            float4 q0 = *(const float4*)(ap);
            float4 q1 = *(const float4*)(ap + 4);
            float4 q2 = *(const float4*)(ap + 8);
            float4 q3 = *(const float4*)(ap + 12);
            f[0]=q0.x; f[1]=q0.y; f[2]=q0.z; f[3]=q0.w;
            f[4]=q1.x; f[5]=q1.y; f[6]=q1.z; f[7]=q1.w;
            f[8]=q2.x; f[9]=q2.y; f[10]=q2.z; f[11]=q2.w;
            f[12]=q3.x; f[13]=q3.y; f[14]=q3.z; f[15]=q3.w;
        } else {
#pragma unroll
            for (int j = 0; j < 16; j++) f[j] = 0.f;
        }
        bf16x8 h0, h1, l0, l1;
#pragma unroll
        for (int j = 0; j < 8; j++) {
            short hh, ll;
            split_bf(f[j], hh, ll);     h0[j] = hh; l0[j] = ll;
            split_bf(f[8 + j], hh, ll); h1[j] = hh; l1[j] = ll;
        }
        float g0[8], g1[8];
        if (bvec) {
            const float* bp0 = B + (size_t)(k0 + kb) * ldb + (n0 + c8);
            const float* bp1 = bp0 + ldb;
            float4 q0 = *(const float4*)(bp0);
            float4 q1 = *(const float4*)(bp0 + 4);
            float4 q2 = *(const float4*)(bp1);
            float4 q3 = *(const float4*)(bp1 + 4);
            g0[0]=q0.x; g0[1]=q0.y; g0[2]=q0.z; g0[3]=q0.w;
            g0[4]=q1.x; g0[5]=q1.y; g0[6]=q1.z; g0[7]=q1.w;
            g1[0]=q2.x; g1[1]=q2.y; g1[2]=q2.z; g1[3]=q2.w;
            g1[4]=q3.x; g1[5]=q3.y; g1[6]=q3.z; g1[7]=q3.w;
        } else {
            const float* bp0 = B + (size_t)(k0 + kb) * ldb;
            const float* bp1 = bp0 + ldb;
#pragma unroll
            for (int j = 0; j < 8; j++) {
                const int nn = n0 + c8 + j;
                g0[j] = (nn < N) ? bp0[nn] : 0.f;
                g1[j] = (nn < N) ? bp1[nn] : 0.f;
            }
        }
        __syncthreads();
        *(bf16x8*)&Ah[ar * 40 + ac]     = h0;
        *(bf16x8*)&Ah[ar * 40 + ac + 8] = h1;
        *(bf16x8*)&Al[ar * 40 + ac]     = l0;
        *(bf16x8*)&Al[ar * 40 + ac + 8] = l1;
#pragma unroll
        for (int j = 0; j < 8; j++) {
            short ha, la, hb, lb;
            split_bf(g0[j], ha, la);
            split_bf(g1[j], hb, lb);
            const int ci = (c8 + j) * 40 + kb;
            *(int*)&Bh[ci] = (int)((unsigned short)ha | ((unsigned)(unsigned short)hb << 16));
            *(int*)&Bl[ci] = (int)((unsigned short)la | ((unsigned)(unsigned short)lb << 16));
        }
        __syncthreads();

        bf16x8 afh[4], afl[4], bfh[4], bfl[4];
#pragma unroll
        for (int fm = 0; fm < 4; fm++) {
            const int idx = (wm + fm * 16 + lm) * 40 + lk * 8;
            afh[fm] = *(bf16x8*)&Ah[idx];
            afl[fm] = *(bf16x8*)&Al[idx];
        }
#pragma unroll
        for (int fn = 0; fn < 4; fn++) {
            const int idx = (wn + fn * 16 + lm) * 40 + lk * 8;
            bfh[fn] = *(bf16x8*)&Bh[idx];
            bfl[fn] = *(bf16x8*)&Bl[idx];
        }
#pragma unroll
        for (int fm = 0; fm < 4; fm++)
#pragma unroll
            for (int fn = 0; fn < 4; fn++) {
                acc[fm][fn] = __builtin_amdgcn_mfma_f32_16x16x32_bf16(afh[fm], bfh[fn], acc[fm][fn], 0, 0, 0);
                acc[fm][fn] = __builtin_amdgcn_mfma_f32_16x16x32_bf16(afh[fm], bfl[fn], acc[fm][fn], 0, 0, 0);
                acc[fm][fn] = __builtin_amdgcn_mfma_f32_16x16x32_bf16(afl[fm], bfh[fn], acc[fm][fn], 0, 0, 0);
            }
    }

#pragma unroll
    for (int fm = 0; fm < 4; fm++) {
#pragma unroll
        for (int fn = 0; fn < 4; fn++) {
            const int col = n0 + wn + fn * 16 + lm;
            if (col >= N) continue;
            const float bb = bias ? bias[col] : 0.f;
#pragma unroll
            for (int r = 0; r < 4; r++) {
                const int row = m0 + wm + fm * 16 + lk * 4 + r;
                if (row >= M) continue;
                const size_t orow = pmap ? (size_t)((row & 63) * TSTEPS + (row >> 6))
                                         : (size_t)row;
                C[orow * ldc + col] = acc[fm][fn][r] + bb;
            }
        }
    }
}

__global__ __launch_bounds__(256) void reduce_partials(
    const float* __restrict__ P, int S, int N,
    const float* __restrict__ bias, float* __restrict__ C, int ldc, int act)
{
    const int idx = blockIdx.x * 256 + threadIdx.x;
    const int total = 64 * N;
    if (idx >= total) return;
    const int m = idx / N;
    const int n = idx - m * N;
    float v = bias ? bias[n] : 0.f;
    for (int s = 0; s < S; s++) v += P[(size_t)s * total + idx];
    if (act == 1) v = fast_tanh(v);
    else if (act == 2) v = fast_sig(v);
    else if (act == 3 && n >= RNND) v = fast_sig(v);
    C[(size_t)m * ldc + n] = v;
}

__global__ __launch_bounds__(256) void reduce_lstm(
    const float* __restrict__ P, int S, const float* __restrict__ bsum,
    float* __restrict__ hn, float* __restrict__ c,
    short* __restrict__ hbh, short* __restrict__ hbl)
{
    const int idx = blockIdx.x * 256 + threadIdx.x;
    const int b = idx >> 10, r = idx & 1023;
    const float* pb = P + (size_t)b * 4096;
    float gi = bsum[r], gf = bsum[1024 + r], gg = bsum[2048 + r], go = bsum[3072 + r];
    for (int s = 0; s < S; s++) {
        const float* q = pb + (size_t)s * 64 * 4096;
        gi += q[r]; gf += q[1024 + r]; gg += q[2048 + r]; go += q[3072 + r];
    }
    const float ig = fast_sig(gi);
    const float fg = fast_sig(gf);
    const float g2 = fast_tanh(gg);
    const float og = fast_sig(go);
    const float cn = fg * c[idx] + ig * g2;
    const float hv = og * fast_tanh(cn);
    c[idx]  = cn;
    hn[idx] = hv;
    if (hbh) {
        short hi, lo;
        split_bf(hv, hi, lo);
        hbh[idx] = hi;
        hbl[idx] = lo;
    }
}

__global__ __launch_bounds__(256) void mean_img(
    const float* __restrict__ img, float* __restrict__ avg)
{
    const int b = blockIdx.x;
    const int d = blockIdx.y * 256 + threadIdx.x;
    const float* p = img + (size_t)b * LIMG * DIMG + d;
    float s = 0.f;
    for (int l = 0; l < LIMG; l++) s += p[(size_t)l * DIMG];
    avg[(size_t)b * DIMG + d] = s * (1.f / 196.f);
}

__global__ __launch_bounds__(256) void concat_w(
    const float* __restrict__ WU, const float* __restrict__ Wfb,
    float* __restrict__ Wug)
{
    const int idx = blockIdx.x * 256 + threadIdx.x;
    if (idx >= 1024 * 3072) return;
    const int k = idx / 3072;
    const int j = idx - k * 3072;
    Wug[idx] = (j < 1024) ? WU[(size_t)k * 1024 + j] : Wfb[(size_t)k * 2048 + (j - 1024)];
}

__global__ __launch_bounds__(256) void concat_b(
    const float* __restrict__ bU, const float* __restrict__ bfb,
    const float* __restrict__ bih, const float* __restrict__ bhh,
    float* __restrict__ bug, float* __restrict__ bsum)
{
    const int j = blockIdx.x * 256 + threadIdx.x;
    if (j < 3072) bug[j] = (j < 1024) ? bU[j] : bfb[j - 1024];
    if (j < 4096) bsum[j] = bih[j] + bhh[j];
}

// ---------------------------------------------------------------------------
// attn_e2: e[b,l] with inline U_h reduce from Wug split-K partials P.
// Block = 4 (b,l) rows; block reduces U_h for its (<=2) batch rows into LDS,
// then each wave computes its row's tanh-dot. Replaces reduce_partials+attn_e.
// ---------------------------------------------------------------------------
__global__ __launch_bounds__(256) void attn_e2(
    const float* __restrict__ P, const float* __restrict__ bug,
    const float* __restrict__ Ws, const float* __restrict__ Wv,
    const float* __restrict__ bv, float* __restrict__ e)
{
    __shared__ float uh2[2][1024];
    const int bid = blockIdx.x, tid = threadIdx.x;
    const int b_lo = (bid * 4) / LIMG;
    const int b_hi = (bid * 4 + 3) / LIMG;

    for (int j = tid; j < 1024; j += 256) {
        float v = bug[j];
        const float* pb = P + (size_t)b_lo * 3072 + j;
#pragma unroll
        for (int s = 0; s < 8; s++) v += pb[(size_t)s * 64 * 3072];
        uh2[0][j] = v;
        if (b_hi != b_lo) {
            float v2 = bug[j];
            const float* pb2 = P + (size_t)b_hi * 3072 + j;
#pragma unroll
            for (int s = 0; s < 8; s++) v2 += pb2[(size_t)s * 64 * 3072];
            uh2[1][j] = v2;
        }
    }
    __syncthreads();

    const int wv   = (bid << 2) + (tid >> 6);
    const int lane = tid & 63;
    const int b    = wv / LIMG;
    const float* uh   = uh2[b - b_lo];
    const float* wrow = Ws + (size_t)wv * RNND;
    float acc = 0.f;
#pragma unroll
    for (int k = lane * 4; k < RNND; k += 256) {
        float4 wq = *(const float4*)(wrow + k);
        float4 uq = *(const float4*)(uh + k);
        float4 vq = *(const float4*)(Wv + k);
        acc += fast_tanh(wq.x + uq.x) * vq.x + fast_tanh(wq.y + uq.y) * vq.y
             + fast_tanh(wq.z + uq.z) * vq.z + fast_tanh(wq.w + uq.w) * vq.w;
    }
#pragma unroll
    for (int off = 32; off > 0; off >>= 1) acc += __shfl_down(acc, off);
    if (lane == 0) e[wv] = acc + bv[0];
}

// ---------------------------------------------------------------------------
// ctx_fuse2: softmax + alphas + x assembly, gate reduced inline from P.
// grid (64, 5): y==0 alphas/emb/h; y in 1..4: 512-wide ctx slice.
// ---------------------------------------------------------------------------
__global__ __launch_bounds__(256) void ctx_fuse2(
    const float* __restrict__ e, const float* __restrict__ P,
    const float* __restrict__ bug, const float* __restrict__ img,
    const float* __restrict__ embt, const int* __restrict__ captions,
    const float* __restrict__ h, float* __restrict__ x,
    float* __restrict__ alphas_out, int t)
{
    __shared__ float al[256];
    __shared__ float red[256];
    const int b = blockIdx.x, y = blockIdx.y, tid = threadIdx.x;

    const float v = (tid < LIMG) ? e[b * LIMG + tid] : -3.0e38f;
    red[tid] = v; __syncthreads();
    for (int s = 128; s > 0; s >>= 1) {
        if (tid < s) red[tid] = fmaxf(red[tid], red[tid + s]);
        __syncthreads();
    }
    const float mx = red[0]; __syncthreads();
    const float ex = (tid < LIMG) ? __expf(v - mx) : 0.f;
    red[tid] = ex; __syncthreads();
    for (int s = 128; s > 0; s >>= 1) {
        if (tid < s) red[tid] += red[tid + s];
        __syncthreads();
    }
    const float inv = 1.f / red[0];
    al[tid] = ex * inv;
    __syncthreads();

    if (y == 0) {
        if (tid < LIMG)
            alphas_out[(size_t)b * (TSTEPS * LIMG) + t * LIMG + tid] = al[tid];
        const int tok = (t == 0) ? 10001 : captions[b * 16 + (t - 1)];
        for (int j = tid; j < EMBD; j += 256)
            x[(size_t)b * 3584 + j] = embt[(size_t)tok * EMBD + j];
        for (int j = tid; j < RNND; j += 256)
            x[(size_t)b * 3584 + 2560 + j] = h[(size_t)b * RNND + j];
    } else {
        const int d0 = (y - 1) * 512 + tid * 2;      // 0..2046
        const float* ib = img + (size_t)b * LIMG * DIMG + d0;
        float a0 = 0.f, a1 = 0.f;
#pragma unroll 4
        for (int l = 0; l < LIMG; l++) {
            float2 q = *(const float2*)(ib + (size_t)l * DIMG);
            a0 = fmaf(al[l], q.x, a0);
            a1 = fmaf(al[l], q.y, a1);
        }
        // inline gate reduce: gate[d] = sig(bug[1024+d] + sum_s P[s][b][1024+d])
        float g0 = bug[1024 + d0], g1 = bug[1024 + d0 + 1];
        const float* pb = P + (size_t)b * 3072 + 1024 + d0;
#pragma unroll
        for (int s = 0; s < 8; s++) {
            g0 += pb[(size_t)s * 64 * 3072];
            g1 += pb[(size_t)s * 64 * 3072 + 1];
        }
        g0 = fast_sig(g0);
        g1 = fast_sig(g1);
        x[(size_t)b * 3584 + EMBD + d0]     = g0 * a0;
        x[(size_t)b * 3584 + EMBD + d0 + 1] = g1 * a1;
    }
}

__global__ __launch_bounds__(256) void attn_e(
    const float* __restrict__ Ws, const float* __restrict__ ug,
    const float* __restrict__ Wv, const float* __restrict__ bv,
    float* __restrict__ e)
{
    const int wv   = (blockIdx.x << 2) + (threadIdx.x >> 6);
    const int lane = threadIdx.x & 63;
    const int b    = wv / LIMG;
    const float* wrow = Ws + (size_t)wv * RNND;
    const float* urow = ug + (size_t)b * 3072;
    float acc = 0.f;
#pragma unroll
    for (int k = lane * 4; k < RNND; k += 256) {
        float4 wq = *(const float4*)(wrow + k);
        float4 uq = *(const float4*)(urow + k);
        float4 vq = *(const float4*)(Wv + k);
        acc += fast_tanh(wq.x + uq.x) * vq.x + fast_tanh(wq.y + uq.y) * vq.y
             + fast_tanh(wq.z + uq.z) * vq.z + fast_tanh(wq.w + uq.w) * vq.w;
    }
#pragma unroll
    for (int off = 32; off > 0; off >>= 1) acc += __shfl_down(acc, off);
    if (lane == 0) e[wv] = acc + bv[0];
}

__global__ __launch_bounds__(256) void softmax_alpha(
    const float* __restrict__ e, float* __restrict__ alpha,
    float* __restrict__ alphas_out, int t)
{
    __shared__ float red[256];
    const int b = blockIdx.x, tid = threadIdx.x;
    const float v = (tid < LIMG) ? e[b * LIMG + tid] : -3.0e38f;
    red[tid] = v; __syncthreads();
    for (int s = 128; s > 0; s >>= 1) {
        if (tid < s) red[tid] = fmaxf(red[tid], red[tid + s]);
        __syncthreads();
    }
    const float mx = red[0]; __syncthreads();
    const float ex = (tid < LIMG) ? __expf(v - mx) : 0.f;
    red[tid] = ex; __syncthreads();
    for (int s = 128; s > 0; s >>= 1) {
        if (tid < s) red[tid] += red[tid + s];
        __syncthreads();
    }
    const float inv = 1.f / red[0];
    if (tid < LIMG) {
        const float a = ex * inv;
        alpha[b * LIMG + tid] = a;
        alphas_out[(size_t)b * (TSTEPS * LIMG) + t * LIMG + tid] = a;
    }
}

__global__ __launch_bounds__(128) void assemble_x(
    const float* __restrict__ img, const float* __restrict__ alpha,
    const float* __restrict__ ug, const float* __restrict__ emb,
    const int* __restrict__ captions, const float* __restrict__ h,
    float* __restrict__ x, int t, int stride)
{
    const int b = blockIdx.x, y = blockIdx.y, tid = threadIdx.x;
    if (y < 4) {
        const int tok = (t == 0) ? 10001 : captions[b * 16 + (t - 1)];
        const int j = y * 128 + tid;
        x[(size_t)b * stride + j] = emb[(size_t)tok * EMBD + j];
    } else if (y < 20) {
        __shared__ float al[LIMG];
        for (int i = tid; i < LIMG; i += 128) al[i] = alpha[b * LIMG + i];
        __syncthreads();
        const int d = (y - 4) * 128 + tid;
        const float* ib = img + (size_t)b * LIMG * DIMG + d;
        float accv = 0.f;
#pragma unroll 4
        for (int l = 0; l < LIMG; l++) accv = fmaf(al[l], ib[(size_t)l * DIMG], accv);
        const float g = ug[(size_t)b * 3072 + 1024 + d];
        x[(size_t)b * stride + EMBD + d] = g * accv;
    } else {
        const int j = (y - 20) * 128 + tid;
        x[(size_t)b * stride + 2560 + j] = h[(size_t)b * RNND + j];
    }
}

extern "C" void kernel_launch(void* const* d_in, const int* in_sizes, int n_in,
                              void* d_out, int out_size, void* d_ws, size_t ws_size,
                              hipStream_t stream)
{
    const float* img      = (const float*)d_in[0];
    const int*   captions = (const int*)d_in[1];
    const float* emb      = (const float*)d_in[2];
    const float* Wih      = (const float*)d_in[3];
    const float* Whh      = (const float*)d_in[4];
    const float* bih      = (const float*)d_in[5];
    const float* bhh      = (const float*)d_in[6];
    const float* Wh0      = (const float*)d_in[7];
    const float* bh0      = (const float*)d_in[8];
    const float* Wc0      = (const float*)d_in[9];
    const float* bc0      = (const float*)d_in[10];
    const float* Wfb      = (const float*)d_in[11];
    const float* bfb      = (const float*)d_in[12];
    const float* Wout     = (const float*)d_in[13];
    const float* bout     = (const float*)d_in[14];
    const float* WU       = (const float*)d_in[15];
    const float* bU       = (const float*)d_in[16];
    const float* WW       = (const float*)d_in[17];
    const float* bW       = (const float*)d_in[18];
    const float* Wv       = (const float*)d_in[19];
    const float* bv       = (const float*)d_in[20];

    float* preds      = (float*)d_out;
    float* alphas_out = preds + (size_t)NB * TSTEPS * VOUTD;

    const size_t NEED = 190000000;

    if (ws_size >= NEED) {
        float* w = (float*)d_ws;
        float* Ws    = w; w += (size_t)12544 * 1024;
        float* ug    = w; w += (size_t)64 * 3072;
        float* P     = w; w += (size_t)8 * 64 * 4096;
        float* e     = w; w += (size_t)64 * LIMG;
        float* alpha = w; w += (size_t)64 * LIMG;
        float* xh    = w; w += (size_t)64 * 3584;
        float* h     = w; w += (size_t)64 * RNND;
        float* c     = w; w += (size_t)64 * RNND;
        float* avg   = w; w += (size_t)64 * DIMG;
        float* bsum  = w; w += 4096;
        float* bug   = w; w += 3072;
        short* u = (short*)w;
        short* Hbh     = u; u += (size_t)1280 * 1024;
        short* Hbl     = u; u += (size_t)1280 * 1024;
        short* WWTh    = u; u += (size_t)1024 * 2048;
        short* WWTl    = u; u += (size_t)1024 * 2048;
        short* WugTh   = u; u += (size_t)3072 * 1024;
        short* WugTl   = u; u += (size_t)3072 * 1024;
        short* WfullTh = u; u += (size_t)4096 * 3584;
        short* WfullTl = u; u += (size_t)4096 * 3584;
        short* WoutTh  = u; u += (size_t)10112 * 1024;
        short* WoutTl  = u; u += (size_t)10112 * 1024;

        mean_img<<<dim3(NB, 8), 256, 0, stream>>>(img, avg);
        gemm64<<<dim3(16, 1, 8), 256, 0, stream>>>(avg, Wh0, nullptr, P, 1024, 2048, 256, 0, 0, 0);
        reduce_partials<<<256, 256, 0, stream>>>(P, 8, 1024, bh0, h, 1024, 1);
        gemm64<<<dim3(16, 1, 8), 256, 0, stream>>>(avg, Wc0, nullptr, P, 1024, 2048, 256, 0, 0, 0);
        reduce_partials<<<256, 256, 0, stream>>>(P, 8, 1024, bc0, c, 1024, 1);
        concat_b<<<16, 256, 0, stream>>>(bU, bfb, bih, bhh, bug, bsum);

        tsplit<<<dim3(32, 16), 256, 0, stream>>>(WW, 1024, WW, 1024, WWTh, WWTl, 1024, 2048, 2048, 0);
        tsplit<<<dim3(16, 48), 256, 0, stream>>>(WU, 1024, Wfb, 2048, WugTh, WugTl, 3072, 1024, 1024, 1024);
        tsplit<<<dim3(56, 64), 256, 0, stream>>>(Wih, 4096, Whh, 4096, WfullTh, WfullTl, 4096, 3584, 2560, 0);
        tsplit<<<dim3(16, 157), 256, 0, stream>>>(Wout, VOUTD, Wout, VOUTD, WoutTh, WoutTl, VOUTD, 1024, 1024, 0);

        // W_s = img @ WW + bW : 64x128 tiles, grid (8, 196)
        gemm_mt<<<dim3(8, 196), 256, 0, stream>>>(img, nullptr, nullptr, WWTh, WWTl,
                                                  bW, Ws, 1024, 2048, 2048, 2048, 1024, 0);

        for (int t = 0; t < TSTEPS; t++) {
            gemm_sk<<<dim3(24, 1, 8), 256, 0, stream>>>(h, WugTh, WugTl, P, 3072, 1024, 1024, 1024, 128);
            attn_e2<<<3136, 256, 0, stream>>>(P, bug, Ws, Wv, bv, e);
            ctx_fuse2<<<dim3(NB, 5), 256, 0, stream>>>(e, P, bug, img, emb, captions, h, xh, alphas_out, t);
            gemm_sk<<<dim3(32, 1, 7), 256, 0, stream>>>(xh, WfullTh, WfullTl, P, 4096, 3584, 3584, 3584, 512);
            reduce_lstm<<<256, 256, 0, stream>>>(P, 7, bsum, h, c,
                                                 Hbh + (size_t)(t + 1) * 65536,
                                                 Hbl + (size_t)(t + 1) * 65536);
        }

        // preds: 64x128 tiles, grid (79, 17), pmap output
        gemm_mt<<<dim3(79, 17), 256, 0, stream>>>(nullptr, Hbh + 65536, Hbl + 65536,
                                                  WoutTh, WoutTl, bout, preds,
                                                  VOUTD, 1024, 1024, 1024, VOUTD, 1);
        (void)ug; (void)alpha;
    } else {
        float* w = (float*)d_ws;
        float* Ws    = w; w += (size_t)12544 * 1024;
        float* ug    = w; w += (size_t)64 * 3072;
        float* P     = w; w += (size_t)12 * 64 * 4096;
        float* e     = w; w += (size_t)64 * LIMG;
        float* alpha = w; w += (size_t)64 * LIMG;
        float* x     = w; w += (size_t)64 * 2560;
        float* Hh    = w; w += (size_t)18 * 64 * RNND;
        float* c     = w; w += (size_t)64 * RNND;
        float* avg   = w; w += (size_t)64 * DIMG;
        float* bsum  = w; w += 4096;
        float* Wug   = w; w += (size_t)1024 * 3072;
        float* bug   = w; w += 3072;

        mean_img<<<dim3(NB, 8), 256, 0, stream>>>(img, avg);
        gemm64<<<dim3(16, 1, 8), 256, 0, stream>>>(avg, Wh0, nullptr, P, 1024, 2048, 256, 0, 0, 0);
        reduce_partials<<<256, 256, 0, stream>>>(P, 8, 1024, bh0, Hh, 1024, 1);
        gemm64<<<dim3(16, 1, 8), 256, 0, stream>>>(avg, Wc0, nullptr, P, 1024, 2048, 256, 0, 0, 0);
        reduce_partials<<<256, 256, 0, stream>>>(P, 8, 1024, bc0, c, 1024, 1);
        concat_b<<<16, 256, 0, stream>>>(bU, bfb, bih, bhh, bug, bsum);
        concat_w<<<12288, 256, 0, stream>>>(WU, Wfb, Wug);
        gemm_mfma3<<<dim3(8, 98), 256, 0, stream>>>(img, WW, bW, Ws,
                                                    12544, 1024, 2048, 2048, 1024, 1024, 0);
        for (int t = 0; t < TSTEPS; t++) {
            const float* hc = Hh + (size_t)t * 64 * RNND;
            float*       hn = Hh + (size_t)(t + 1) * 64 * RNND;
            gemm64<<<dim3(48, 1, 8), 256, 0, stream>>>(hc, Wug, nullptr, P, 3072, 1024, 128, 0, 0, 0);
            reduce_partials<<<768, 256, 0, stream>>>(P, 8, 3072, bug, ug, 3072, 3);
            attn_e<<<3136, 256, 0, stream>>>(Ws, ug, Wv, bv, e);
            softmax_alpha<<<NB, 256, 0, stream>>>(e, alpha, alphas_out, t);
            assemble_x<<<dim3(NB, 20), 128, 0, stream>>>(img, alpha, ug, emb, captions, hc, x, t, 2560);
            gemm64<<<dim3(64, 1, 8), 256, 0, stream>>>(x, Wih, nullptr, P, 4096, 2560, 320, 0, 0, 0);
            gemm64<<<dim3(64, 1, 4), 256, 0, stream>>>(hc, Whh, nullptr, P + (size_t)8 * 64 * 4096,
                                                       4096, 1024, 256, 0, 0, 0);
            reduce_lstm<<<256, 256, 0, stream>>>(P, 12, bsum, hn, c, nullptr, nullptr);
        }
        gemm_mfma3<<<dim3(79, 9), 256, 0, stream>>>(Hh + (size_t)64 * RNND, Wout, bout, preds,
                                                    TSTEPS * 64, VOUTD, 1024, 1024, VOUTD, VOUTD, 1);
    }
}

// Round 15
// 1773.538 us; speedup vs baseline: 1.2757x; 1.0087x over previous
//
#include <hip/hip_runtime.h>
#include <cstdint>

#define NB    64
#define LIMG  196
#define DIMG  2048
#define RNND  1024
#define EMBD  512
#define TSTEPS 17
#define VOUTD 10003

typedef short bf16x8 __attribute__((ext_vector_type(8)));
typedef float f32x4  __attribute__((ext_vector_type(4)));

__device__ __forceinline__ float fast_sig(float x) {
    return 1.f / (1.f + __expf(-x));
}
__device__ __forceinline__ float fast_tanh(float x) {
    float ax = fabsf(x);
    float e  = __expf(2.f * ax);
    float r  = 1.f - 2.f / (e + 1.f);
    return copysignf(r, x);
}
__device__ __forceinline__ void split_bf(float x, short& hi, short& lo) {
    unsigned u  = __float_as_uint(x);
    unsigned hb = u & 0xffff0000u;
    hi = (short)(u >> 16);
    float r = x - __uint_as_float(hb);
    lo = (short)(__float_as_uint(r) >> 16);
}
__device__ __forceinline__ short f2bf_rne(float x) {
    unsigned u = __float_as_uint(x);
    return (short)((u + 0x7FFFu + ((u >> 16) & 1u)) >> 16);
}
__device__ __forceinline__ float bf2f(short s) {
    return __uint_as_float(((unsigned)(unsigned short)s) << 16);
}

// ---------------------------------------------------------------------------
// Transpose + bf16 hi/lo split of weights
// ---------------------------------------------------------------------------
__global__ __launch_bounds__(256) void tsplit(
    const float* __restrict__ S1, int ld1,
    const float* __restrict__ S2, int ld2,
    short* __restrict__ outh, short* __restrict__ outl,
    int N, int K, int ksplit, int nsplit)
{
    __shared__ float T[64][65];
    const int k0 = blockIdx.x * 64, n0 = blockIdx.y * 64;
    const int tid = threadIdx.x;
    const int rr = tid >> 2;
    const int cc = (tid & 3) * 16;
    const int kk = k0 + rr;
    const int nn = n0 + cc;
    const float* rp; int col;
    if (nsplit > 0) {
        if (nn >= nsplit) { rp = S2 + (size_t)kk * ld2; col = nn - nsplit; }
        else              { rp = S1 + (size_t)kk * ld1; col = nn; }
    } else {
        if (kk < ksplit)  { rp = S1 + (size_t)kk * ld1; col = nn; }
        else              { rp = S2 + (size_t)(kk - ksplit) * ld2; col = nn; }
    }
#pragma unroll
    for (int j = 0; j < 16; j++)
        T[rr][cc + j] = (nn + j < N) ? rp[col + j] : 0.f;
    __syncthreads();
    const int wn = tid >> 2;
    const int wk = (tid & 3) * 16;
    const int gn = n0 + wn;
    if (gn >= N) return;
    bf16x8 h0, h1, l0, l1;
#pragma unroll
    for (int j = 0; j < 8; j++) {
        short hh, ll;
        split_bf(T[wk + j][wn], hh, ll);     h0[j] = hh; l0[j] = ll;
        split_bf(T[wk + 8 + j][wn], hh, ll); h1[j] = hh; l1[j] = ll;
    }
    const size_t o = (size_t)gn * K + k0 + wk;
    *(bf16x8*)&outh[o]     = h0;
    *(bf16x8*)&outh[o + 8] = h1;
    *(bf16x8*)&outl[o]     = l0;
    *(bf16x8*)&outl[o + 8] = l1;
}

// ---------------------------------------------------------------------------
// m-tiled 64x128 bf16x3 MFMA GEMM. grid (N/128 ceil, M/64).
// obf=1: write RNE bf16 to (short*)C (ldc in elements).
// ---------------------------------------------------------------------------
__global__ __launch_bounds__(256) void gemm_mt(
    const float* __restrict__ Af,
    const short* __restrict__ Ah16, const short* __restrict__ Al16,
    const short* __restrict__ Bh16, const short* __restrict__ Bl16,
    const float* __restrict__ bias, float* __restrict__ C,
    int N, int K, int lda, int ldb, int ldc, int pmap, int obf)
{
    __shared__ short Ah[64 * 40], Al[64 * 40];
    __shared__ short Bh[128 * 40], Bl[128 * 40];

    const int tid = threadIdx.x;
    const int n0  = blockIdx.x * 128;
    const int m0  = blockIdx.y * 64;

    const int lane = tid & 63;
    const int w    = tid >> 6;
    const int wn   = w * 32;
    const int lm   = lane & 15;
    const int lk   = lane >> 4;

    const int a_r = tid >> 2;
    const int a_c = (tid & 3) * 8;
    const int b_r = tid >> 1;
    const int b_c = (tid & 1) * 16;

    f32x4 acc[4][2];
#pragma unroll
    for (int i = 0; i < 4; i++)
#pragma unroll
        for (int j = 0; j < 2; j++) acc[i][j] = (f32x4)0.f;

    bf16x8 rah, ral, rbh0, rbh1, rbl0, rbl1;
    auto load_tile = [&](int k0) {
        if (Af) {
            const float* ap = Af + (size_t)(m0 + a_r) * lda + (k0 + a_c);
            float4 q0 = *(const float4*)(ap);
            float4 q1 = *(const float4*)(ap + 4);
            float f[8] = {q0.x, q0.y, q0.z, q0.w, q1.x, q1.y, q1.z, q1.w};
#pragma unroll
            for (int j = 0; j < 8; j++) {
                short hh, ll;
                split_bf(f[j], hh, ll); rah[j] = hh; ral[j] = ll;
            }
        } else {
            rah = *(const bf16x8*)(Ah16 + (size_t)(m0 + a_r) * lda + (k0 + a_c));
            ral = *(const bf16x8*)(Al16 + (size_t)(m0 + a_r) * lda + (k0 + a_c));
        }
        const short* pb = Bh16 + (size_t)(n0 + b_r) * ldb + (k0 + b_c);
        rbh0 = *(const bf16x8*)pb; rbh1 = *(const bf16x8*)(pb + 8);
        const short* qb = Bl16 + (size_t)(n0 + b_r) * ldb + (k0 + b_c);
        rbl0 = *(const bf16x8*)qb; rbl1 = *(const bf16x8*)(qb + 8);
    };

    load_tile(0);
    for (int k0 = 0; k0 < K; k0 += 32) {
        __syncthreads();
        *(bf16x8*)&Ah[a_r * 40 + a_c] = rah;
        *(bf16x8*)&Al[a_r * 40 + a_c] = ral;
        *(bf16x8*)&Bh[b_r * 40 + b_c]     = rbh0;
        *(bf16x8*)&Bh[b_r * 40 + b_c + 8] = rbh1;
        *(bf16x8*)&Bl[b_r * 40 + b_c]     = rbl0;
        *(bf16x8*)&Bl[b_r * 40 + b_c + 8] = rbl1;
        __syncthreads();
        if (k0 + 32 < K) load_tile(k0 + 32);   // prefetch hides under MFMAs

        bf16x8 afh[4], afl[4], bfh[2], bfl[2];
#pragma unroll
        for (int fm = 0; fm < 4; fm++) {
            const int idx = (fm * 16 + lm) * 40 + lk * 8;
            afh[fm] = *(bf16x8*)&Ah[idx];
            afl[fm] = *(bf16x8*)&Al[idx];
        }
#pragma unroll
        for (int fn = 0; fn < 2; fn++) {
            const int idx = (wn + fn * 16 + lm) * 40 + lk * 8;
            bfh[fn] = *(bf16x8*)&Bh[idx];
            bfl[fn] = *(bf16x8*)&Bl[idx];
        }
#pragma unroll
        for (int fm = 0; fm < 4; fm++)
#pragma unroll
            for (int fn = 0; fn < 2; fn++) {
                acc[fm][fn] = __builtin_amdgcn_mfma_f32_16x16x32_bf16(afh[fm], bfh[fn], acc[fm][fn], 0, 0, 0);
                acc[fm][fn] = __builtin_amdgcn_mfma_f32_16x16x32_bf16(afh[fm], bfl[fn], acc[fm][fn], 0, 0, 0);
                acc[fm][fn] = __builtin_amdgcn_mfma_f32_16x16x32_bf16(afl[fm], bfh[fn], acc[fm][fn], 0, 0, 0);
            }
    }

#pragma unroll
    for (int fm = 0; fm < 4; fm++)
#pragma unroll
        for (int fn = 0; fn < 2; fn++) {
            const int col = n0 + wn + fn * 16 + lm;
            if (col >= N) continue;
            const float bb = bias ? bias[col] : 0.f;
#pragma unroll
            for (int r = 0; r < 4; r++) {
                const int row = m0 + fm * 16 + lk * 4 + r;
                const size_t orow = pmap ? (size_t)((row & 63) * TSTEPS + (row >> 6))
                                         : (size_t)row;
                const float v = acc[fm][fn][r] + bb;
                if (obf) ((short*)C)[orow * ldc + col] = f2bf_rne(v);
                else     C[orow * ldc + col] = v;
            }
        }
}

// ---------------------------------------------------------------------------
// Skinny bf16x3 MFMA GEMM, split-K partials.
// ---------------------------------------------------------------------------
__global__ __launch_bounds__(256) void gemm_sk(
    const float* __restrict__ A,
    const short* __restrict__ Bh16, const short* __restrict__ Bl16,
    float* __restrict__ P, int N, int K, int lda, int ldb, int Kc)
{
    __shared__ short Ah[64 * 40], Al[64 * 40];
    __shared__ short Bh[128 * 40], Bl[128 * 40];

    const int tid = threadIdx.x;
    const int n0  = blockIdx.x * 128;
    const int s   = blockIdx.z;
    const int kb  = s * Kc;

    const int lane = tid & 63;
    const int w    = tid >> 6;
    const int wn   = w * 32;
    const int lm   = lane & 15;
    const int lk   = lane >> 4;

    const int a_r = tid >> 2;
    const int a_c = (tid & 3) * 8;
    const int b_r = tid >> 1;
    const int b_c = (tid & 1) * 16;

    f32x4 acc[4][2];
#pragma unroll
    for (int i = 0; i < 4; i++)
#pragma unroll
        for (int j = 0; j < 2; j++) acc[i][j] = (f32x4)0.f;

    for (int k0 = kb; k0 < kb + Kc; k0 += 32) {
        const float* ap = A + (size_t)a_r * lda + (k0 + a_c);
        float4 q0 = *(const float4*)(ap);
        float4 q1 = *(const float4*)(ap + 4);
        float f[8] = {q0.x, q0.y, q0.z, q0.w, q1.x, q1.y, q1.z, q1.w};
        bf16x8 ah, al;
#pragma unroll
        for (int j = 0; j < 8; j++) {
            short hh, ll;
            split_bf(f[j], hh, ll); ah[j] = hh; al[j] = ll;
        }
        const short* pb = Bh16 + (size_t)(n0 + b_r) * ldb + (k0 + b_c);
        bf16x8 bh0 = *(const bf16x8*)pb, bh1 = *(const bf16x8*)(pb + 8);
        const short* qb = Bl16 + (size_t)(n0 + b_r) * ldb + (k0 + b_c);
        bf16x8 bl0 = *(const bf16x8*)qb, bl1 = *(const bf16x8*)(qb + 8);

        __syncthreads();
        *(bf16x8*)&Ah[a_r * 40 + a_c] = ah;
        *(bf16x8*)&Al[a_r * 40 + a_c] = al;
        *(bf16x8*)&Bh[b_r * 40 + b_c]     = bh0;
        *(bf16x8*)&Bh[b_r * 40 + b_c + 8] = bh1;
        *(bf16x8*)&Bl[b_r * 40 + b_c]     = bl0;
        *(bf16x8*)&Bl[b_r * 40 + b_c + 8] = bl1;
        __syncthreads();

        bf16x8 afh[4], afl[4], bfh[2], bfl[2];
#pragma unroll
        for (int fm = 0; fm < 4; fm++) {
            const int idx = (fm * 16 + lm) * 40 + lk * 8;
            afh[fm] = *(bf16x8*)&Ah[idx];
            afl[fm] = *(bf16x8*)&Al[idx];
        }
#pragma unroll
        for (int fn = 0; fn < 2; fn++) {
            const int idx = (wn + fn * 16 + lm) * 40 + lk * 8;
            bfh[fn] = *(bf16x8*)&Bh[idx];
            bfl[fn] = *(bf16x8*)&Bl[idx];
        }
#pragma unroll
        for (int fm = 0; fm < 4; fm++)
#pragma unroll
            for (int fn = 0; fn < 2; fn++) {
                acc[fm][fn] = __builtin_amdgcn_mfma_f32_16x16x32_bf16(afh[fm], bfh[fn], acc[fm][fn], 0, 0, 0);
                acc[fm][fn] = __builtin_amdgcn_mfma_f32_16x16x32_bf16(afh[fm], bfl[fn], acc[fm][fn], 0, 0, 0);
                acc[fm][fn] = __builtin_amdgcn_mfma_f32_16x16x32_bf16(afl[fm], bfh[fn], acc[fm][fn], 0, 0, 0);
            }
    }

    float* Ps = P + (size_t)s * 64 * N;
#pragma unroll
    for (int fm = 0; fm < 4; fm++)
#pragma unroll
        for (int fn = 0; fn < 2; fn++) {
            const int col = n0 + wn + fn * 16 + lm;
#pragma unroll
            for (int r = 0; r < 4; r++) {
                const int row = fm * 16 + lk * 4 + r;
                Ps[(size_t)row * N + col] = acc[fm][fn][r];
            }
        }
}

// ---------------------------------------------------------------------------
// fp32 tiled GEMM (h0/c0 init + fallback)
// ---------------------------------------------------------------------------
__global__ __launch_bounds__(256) void gemm64(
    const float* __restrict__ A, const float* __restrict__ B,
    const float* __restrict__ bias, float* __restrict__ C,
    int N, int K, int Kc, int ldc, int act, int direct)
{
    __shared__ float As[16][64];
    __shared__ float Bs[16][68];

    const int tid = threadIdx.x;
    const int n0  = blockIdx.x * 64;
    const int m0  = blockIdx.y * 64;
    const int s   = blockIdx.z;
    const int kb  = s * Kc;
    const int ke  = min(K, kb + Kc);

    const int tm = (tid >> 4) << 2;
    const int tn = (tid & 15) << 2;

    float acc[4][4];
#pragma unroll
    for (int i = 0; i < 4; i++)
#pragma unroll
        for (int j = 0; j < 4; j++) acc[i][j] = 0.f;

    const int a_m = tid >> 2;
    const int a_k = (tid & 3) << 2;
    const int b_k = tid >> 4;
    const int b_n = (tid & 15) << 2;
    const bool n4 = ((N & 3) == 0);

    for (int k0 = kb; k0 < ke; k0 += 16) {
        float4 av = *(const float4*)(A + (size_t)(m0 + a_m) * K + (k0 + a_k));
        float4 bv;
        {
            const int nn = n0 + b_n;
            const float* brow = B + (size_t)(k0 + b_k) * N;
            if (n4) {
                bv = (nn < N) ? *(const float4*)(brow + nn) : make_float4(0.f,0.f,0.f,0.f);
            } else {
                bv.x = (nn + 0 < N) ? brow[nn + 0] : 0.f;
                bv.y = (nn + 1 < N) ? brow[nn + 1] : 0.f;
                bv.z = (nn + 2 < N) ? brow[nn + 2] : 0.f;
                bv.w = (nn + 3 < N) ? brow[nn + 3] : 0.f;
            }
        }
        __syncthreads();
        As[a_k + 0][a_m] = av.x;
        As[a_k + 1][a_m] = av.y;
        As[a_k + 2][a_m] = av.z;
        As[a_k + 3][a_m] = av.w;
        *(float4*)&Bs[b_k][b_n] = bv;
        __syncthreads();
#pragma unroll
        for (int k = 0; k < 16; k++) {
            float4 a4 = *(const float4*)&As[k][tm];
            float4 b4 = *(const float4*)&Bs[k][tn];
            acc[0][0] = fmaf(a4.x, b4.x, acc[0][0]);
            acc[0][1] = fmaf(a4.x, b4.y, acc[0][1]);
            acc[0][2] = fmaf(a4.x, b4.z, acc[0][2]);
            acc[0][3] = fmaf(a4.x, b4.w, acc[0][3]);
            acc[1][0] = fmaf(a4.y, b4.x, acc[1][0]);
            acc[1][1] = fmaf(a4.y, b4.y, acc[1][1]);
            acc[1][2] = fmaf(a4.y, b4.z, acc[1][2]);
            acc[1][3] = fmaf(a4.y, b4.w, acc[1][3]);
            acc[2][0] = fmaf(a4.z, b4.x, acc[2][0]);
            acc[2][1] = fmaf(a4.z, b4.y, acc[2][1]);
            acc[2][2] = fmaf(a4.z, b4.z, acc[2][2]);
            acc[2][3] = fmaf(a4.z, b4.w, acc[2][3]);
            acc[3][0] = fmaf(a4.w, b4.x, acc[3][0]);
            acc[3][1] = fmaf(a4.w, b4.y, acc[3][1]);
            acc[3][2] = fmaf(a4.w, b4.z, acc[3][2]);
            acc[3][3] = fmaf(a4.w, b4.w, acc[3][3]);
        }
    }

    if (direct) {
#pragma unroll
        for (int i = 0; i < 4; i++) {
            const int m = m0 + tm + i;
            const size_t row = (size_t)m * ldc;
#pragma unroll
            for (int j = 0; j < 4; j++) {
                const int n = n0 + tn + j;
                if (n < N) {
                    float v = acc[i][j] + (bias ? bias[n] : 0.f);
                    if (act == 1) v = fast_tanh(v);
                    else if (act == 2) v = fast_sig(v);
                    C[row + n] = v;
                }
            }
        }
    } else {
        float* Pp = C + (size_t)s * 64 * N;
#pragma unroll
        for (int i = 0; i < 4; i++) {
#pragma unroll
            for (int j = 0; j < 4; j++) {
                const int n = n0 + tn + j;
                if (n < N) Pp[(size_t)(tm + i) * N + n] = acc[i][j];
            }
        }
    }
}

// fallback big GEMM (round-3, validated)
__global__ __launch_bounds__(256) void gemm_mfma3(
    const float* __restrict__ A, const float* __restrict__ B,
    const float* __restrict__ bias, float* __restrict__ C,
    int M, int N, int K, int lda, int ldb, int ldc, int pmap)
{
    __shared__ short Ah[128 * 40], Al[128 * 40];
    __shared__ short Bh[128 * 40], Bl[128 * 40];

    const int tid = threadIdx.x;
    const int n0  = blockIdx.x * 128;
    const int m0  = blockIdx.y * 128;

    const int lane = tid & 63;
    const int w    = tid >> 6;
    const int wm   = (w >> 1) * 64;
    const int wn   = (w & 1) * 64;
    const int lm   = lane & 15;
    const int lk   = lane >> 4;

    const int ar = tid >> 1;
    const int ac = (tid & 1) * 16;
    const int kb = (tid & 15) * 2;
    const int c8 = (tid >> 4) * 8;

    const bool bvec = ((ldb & 3) == 0) && (n0 + 128 <= N);

    f32x4 acc[4][4];
#pragma unroll
    for (int i = 0; i < 4; i++)
#pragma unroll
        for (int j = 0; j < 4; j++) acc[i][j] = (f32x4)0.f;

    for (int k0 = 0; k0 < K; k0 += 32) {
        float f[16];
        if (m0 + ar < M) {
            const float* ap = A + (size_t)(m0 + ar) * lda + (k0 + ac);
            float4 q0 = *(const float4*)(ap);
            float4 q1 = *(const float4*)(ap + 4);
            float4 q2 = *(const float4*)(ap + 8);
            float4 q3 = *(const float4*)(ap + 12);
            f[0]=q0.x; f[1]=q0.y; f[2]=q0.z; f[3]=q0.w;
            f[4]=q1.x; f[5]=q1.y; f[6]=q1.z; f[7]=q1.w;
            f[8]=q2.x; f[9]=q2.y; f[10]=q2.z; f[11]=q2.w;
            f[12]=q3.x; f[13]=q3.y; f[14]=q3.z; f[15]=q3.w;
        } else {
#pragma unroll
            for (int j = 0; j < 16; j++) f[j] = 0.f;
        }
        bf16x8 h0, h1, l0, l1;
#pragma unroll
        for (int j = 0; j < 8; j++) {
            short hh, ll;
            split_bf(f[j], hh, ll);     h0[j] = hh; l0[j] = ll;
            split_bf(f[8 + j], hh, ll); h1[j] = hh; l1[j] = ll;
        }
        float g0[8], g1[8];
        if (bvec) {
            const float* bp0 = B + (size_t)(k0 + kb) * ldb + (n0 + c8);
            const float* bp1 = bp0 + ldb;
            float4 q0 = *(const float4*)(bp0);
            float4 q1 = *(const float4*)(bp0 + 4);
            float4 q2 = *(const float4*)(bp1);
            float4 q3 = *(const float4*)(bp1 + 4);
            g0[0]=q0.x; g0[1]=q0.y; g0[2]=q0.z; g0[3]=q0.w;
            g0[4]=q1.x; g0[5]=q1.y; g0[6]=q1.z; g0[7]=q1.w;
            g1[0]=q2.x; g1[1]=q2.y; g1[2]=q2.z; g1[3]=q2.w;
            g1[4]=q3.x; g1[5]=q3.y; g1[6]=q3.z; g1[7]=q3.w;
        } else {
            const float* bp0 = B + (size_t)(k0 + kb) * ldb;
            const float* bp1 = bp0 + ldb;
#pragma unroll
            for (int j = 0; j < 8; j++) {
                const int nn = n0 + c8 + j;
                g0[j] = (nn < N) ? bp0[nn] : 0.f;
                g1[j] = (nn < N) ? bp1[nn] : 0.f;
            }
        }
        __syncthreads();
        *(bf16x8*)&Ah[ar * 40 + ac]     = h0;
        *(bf16x8*)&Ah[ar * 40 + ac + 8] = h1;
        *(bf16x8*)&Al[ar * 40 + ac]     = l0;
        *(bf16x8*)&Al[ar * 40 + ac + 8] = l1;
#pragma unroll
        for (int j = 0; j < 8; j++) {
            short ha, la, hb, lb;
            split_bf(g0[j], ha, la);
            split_bf(g1[j], hb, lb);
            const int ci = (c8 + j) * 40 + kb;
            *(int*)&Bh[ci] = (int)((unsigned short)ha | ((unsigned)(unsigned short)hb << 16));
            *(int*)&Bl[ci] = (int)((unsigned short)la | ((unsigned)(unsigned short)lb << 16));
        }
        __syncthreads();

        bf16x8 afh[4], afl[4], bfh[4], bfl[4];
#pragma unroll
        for (int fm = 0; fm < 4; fm++) {
            const int idx = (wm + fm * 16 + lm) * 40 + lk * 8;
            afh[fm] = *(bf16x8*)&Ah[idx];
            afl[fm] = *(bf16x8*)&Al[idx];
        }
#pragma unroll
        for (int fn = 0; fn < 4; fn++) {
            const int idx = (wn + fn * 16 + lm) * 40 + lk * 8;
            bfh[fn] = *(bf16x8*)&Bh[idx];
            bfl[fn] = *(bf16x8*)&Bl[idx];
        }
#pragma unroll
        for (int fm = 0; fm < 4; fm++)
#pragma unroll
            for (int fn = 0; fn < 4; fn++) {
                acc[fm][fn] = __builtin_amdgcn_mfma_f32_16x16x32_bf16(afh[fm], bfh[fn], acc[fm][fn], 0, 0, 0);
                acc[fm][fn] = __builtin_amdgcn_mfma_f32_16x16x32_bf16(afh[fm], bfl[fn], acc[fm][fn], 0, 0, 0);
                acc[fm][fn] = __builtin_amdgcn_mfma_f32_16x16x32_bf16(afl[fm], bfh[fn], acc[fm][fn], 0, 0, 0);
            }
    }

#pragma unroll
    for (int fm = 0; fm < 4; fm++) {
#pragma unroll
        for (int fn = 0; fn < 4; fn++) {
            const int col = n0 + wn + fn * 16 + lm;
            if (col >= N) continue;
            const float bb = bias ? bias[col] : 0.f;
#pragma unroll
            for (int r = 0; r < 4; r++) {
                const int row = m0 + wm + fm * 16 + lk * 4 + r;
                if (row >= M) continue;
                const size_t orow = pmap ? (size_t)((row & 63) * TSTEPS + (row >> 6))
                                         : (size_t)row;
                C[orow * ldc + col] = acc[fm][fn][r] + bb;
            }
        }
    }
}

__global__ __launch_bounds__(256) void reduce_partials(
    const float* __restrict__ P, int S, int N,
    const float* __restrict__ bias, float* __restrict__ C, int ldc, int act)
{
    const int idx = blockIdx.x * 256 + threadIdx.x;
    const int total = 64 * N;
    if (idx >= total) return;
    const int m = idx / N;
    const int n = idx - m * N;
    float v = bias ? bias[n] : 0.f;
    for (int s = 0; s < S; s++) v += P[(size_t)s * total + idx];
    if (act == 1) v = fast_tanh(v);
    else if (act == 2) v = fast_sig(v);
    else if (act == 3 && n >= RNND) v = fast_sig(v);
    C[(size_t)m * ldc + n] = v;
}

__global__ __launch_bounds__(256) void reduce_lstm(
    const float* __restrict__ P, int S, const float* __restrict__ bsum,
    float* __restrict__ hn, float* __restrict__ c,
    short* __restrict__ hbh, short* __restrict__ hbl)
{
    const int idx = blockIdx.x * 256 + threadIdx.x;
    const int b = idx >> 10, r = idx & 1023;
    const float* pb = P + (size_t)b * 4096;
    float gi = bsum[r], gf = bsum[1024 + r], gg = bsum[2048 + r], go = bsum[3072 + r];
    for (int s = 0; s < S; s++) {
        const float* q = pb + (size_t)s * 64 * 4096;
        gi += q[r]; gf += q[1024 + r]; gg += q[2048 + r]; go += q[3072 + r];
    }
    const float ig = fast_sig(gi);
    const float fg = fast_sig(gf);
    const float g2 = fast_tanh(gg);
    const float og = fast_sig(go);
    const float cn = fg * c[idx] + ig * g2;
    const float hv = og * fast_tanh(cn);
    c[idx]  = cn;
    hn[idx] = hv;
    if (hbh) {
        short hi, lo;
        split_bf(hv, hi, lo);
        hbh[idx] = hi;
        hbl[idx] = lo;
    }
}

__global__ __launch_bounds__(256) void mean_img(
    const float* __restrict__ img, float* __restrict__ avg)
{
    const int b = blockIdx.x;
    const int d = blockIdx.y * 256 + threadIdx.x;
    const float* p = img + (size_t)b * LIMG * DIMG + d;
    float s = 0.f;
    for (int l = 0; l < LIMG; l++) s += p[(size_t)l * DIMG];
    avg[(size_t)b * DIMG + d] = s * (1.f / 196.f);
}

__global__ __launch_bounds__(256) void concat_w(
    const float* __restrict__ WU, const float* __restrict__ Wfb,
    float* __restrict__ Wug)
{
    const int idx = blockIdx.x * 256 + threadIdx.x;
    if (idx >= 1024 * 3072) return;
    const int k = idx / 3072;
    const int j = idx - k * 3072;
    Wug[idx] = (j < 1024) ? WU[(size_t)k * 1024 + j] : Wfb[(size_t)k * 2048 + (j - 1024)];
}

__global__ __launch_bounds__(256) void concat_b(
    const float* __restrict__ bU, const float* __restrict__ bfb,
    const float* __restrict__ bih, const float* __restrict__ bhh,
    float* __restrict__ bug, float* __restrict__ bsum)
{
    const int j = blockIdx.x * 256 + threadIdx.x;
    if (j < 3072) bug[j] = (j < 1024) ? bU[j] : bfb[j - 1024];
    if (j < 4096) bsum[j] = bih[j] + bhh[j];
}

// ---------------------------------------------------------------------------
// attn_e2: e[b,l] with inline U_h reduce; Ws stored as bf16.
// ---------------------------------------------------------------------------
__global__ __launch_bounds__(256) void attn_e2(
    const float* __restrict__ P, const float* __restrict__ bug,
    const short* __restrict__ Ws, const float* __restrict__ Wv,
    const float* __restrict__ bv, float* __restrict__ e)
{
    __shared__ float uh2[2][1024];
    const int bid = blockIdx.x, tid = threadIdx.x;
    const int b_lo = (bid * 4) / LIMG;
    const int b_hi = (bid * 4 + 3) / LIMG;

    for (int j = tid; j < 1024; j += 256) {
        float v = bug[j];
        const float* pb = P + (size_t)b_lo * 3072 + j;
#pragma unroll
        for (int s = 0; s < 8; s++) v += pb[(size_t)s * 64 * 3072];
        uh2[0][j] = v;
        if (b_hi != b_lo) {
            float v2 = bug[j];
            const float* pb2 = P + (size_t)b_hi * 3072 + j;
#pragma unroll
            for (int s = 0; s < 8; s++) v2 += pb2[(size_t)s * 64 * 3072];
            uh2[1][j] = v2;
        }
    }
    __syncthreads();

    const int wv   = (bid << 2) + (tid >> 6);
    const int lane = tid & 63;
    const int b    = wv / LIMG;
    const float* uh   = uh2[b - b_lo];
    const short* wrow = Ws + (size_t)wv * RNND;
    float acc = 0.f;
#pragma unroll
    for (int k = lane * 4; k < RNND; k += 256) {
        short4 wq = *(const short4*)(wrow + k);
        float4 uq = *(const float4*)(uh + k);
        float4 vq = *(const float4*)(Wv + k);
        acc += fast_tanh(bf2f(wq.x) + uq.x) * vq.x + fast_tanh(bf2f(wq.y) + uq.y) * vq.y
             + fast_tanh(bf2f(wq.z) + uq.z) * vq.z + fast_tanh(bf2f(wq.w) + uq.w) * vq.w;
    }
#pragma unroll
    for (int off = 32; off > 0; off >>= 1) acc += __shfl_down(acc, off);
    if (lane == 0) e[wv] = acc + bv[0];
}

// ---------------------------------------------------------------------------
// ctx_fuse2: softmax + alphas + x assembly, gate reduced inline from P.
// ---------------------------------------------------------------------------
__global__ __launch_bounds__(256) void ctx_fuse2(
    const float* __restrict__ e, const float* __restrict__ P,
    const float* __restrict__ bug, const float* __restrict__ img,
    const float* __restrict__ embt, const int* __restrict__ captions,
    const float* __restrict__ h, float* __restrict__ x,
    float* __restrict__ alphas_out, int t)
{
    __shared__ float al[256];
    __shared__ float red[256];
    const int b = blockIdx.x, y = blockIdx.y, tid = threadIdx.x;

    const float v = (tid < LIMG) ? e[b * LIMG + tid] : -3.0e38f;
    red[tid] = v; __syncthreads();
    for (int s = 128; s > 0; s >>= 1) {
        if (tid < s) red[tid] = fmaxf(red[tid], red[tid + s]);
        __syncthreads();
    }
    const float mx = red[0]; __syncthreads();
    const float ex = (tid < LIMG) ? __expf(v - mx) : 0.f;
    red[tid] = ex; __syncthreads();
    for (int s = 128; s > 0; s >>= 1) {
        if (tid < s) red[tid] += red[tid + s];
        __syncthreads();
    }
    const float inv = 1.f / red[0];
    al[tid] = ex * inv;
    __syncthreads();

    if (y == 0) {
        if (tid < LIMG)
            alphas_out[(size_t)b * (TSTEPS * LIMG) + t * LIMG + tid] = al[tid];
        const int tok = (t == 0) ? 10001 : captions[b * 16 + (t - 1)];
        for (int j = tid; j < EMBD; j += 256)
            x[(size_t)b * 3584 + j] = embt[(size_t)tok * EMBD + j];
        for (int j = tid; j < RNND; j += 256)
            x[(size_t)b * 3584 + 2560 + j] = h[(size_t)b * RNND + j];
    } else {
        const int d0 = (y - 1) * 512 + tid * 2;
        const float* ib = img + (size_t)b * LIMG * DIMG + d0;
        float a0 = 0.f, a1 = 0.f;
#pragma unroll 4
        for (int l = 0; l < LIMG; l++) {
            float2 q = *(const float2*)(ib + (size_t)l * DIMG);
            a0 = fmaf(al[l], q.x, a0);
            a1 = fmaf(al[l], q.y, a1);
        }
        float g0 = bug[1024 + d0], g1 = bug[1024 + d0 + 1];
        const float* pb = P + (size_t)b * 3072 + 1024 + d0;
#pragma unroll
        for (int s = 0; s < 8; s++) {
            g0 += pb[(size_t)s * 64 * 3072];
            g1 += pb[(size_t)s * 64 * 3072 + 1];
        }
        g0 = fast_sig(g0);
        g1 = fast_sig(g1);
        x[(size_t)b * 3584 + EMBD + d0]     = g0 * a0;
        x[(size_t)b * 3584 + EMBD + d0 + 1] = g1 * a1;
    }
}

__global__ __launch_bounds__(256) void attn_e(
    const float* __restrict__ Ws, const float* __restrict__ ug,
    const float* __restrict__ Wv, const float* __restrict__ bv,
    float* __restrict__ e)
{
    const int wv   = (blockIdx.x << 2) + (threadIdx.x >> 6);
    const int lane = threadIdx.x & 63;
    const int b    = wv / LIMG;
    const float* wrow = Ws + (size_t)wv * RNND;
    const float* urow = ug + (size_t)b * 3072;
    float acc = 0.f;
#pragma unroll
    for (int k = lane * 4; k < RNND; k += 256) {
        float4 wq = *(const float4*)(wrow + k);
        float4 uq = *(const float4*)(urow + k);
        float4 vq = *(const float4*)(Wv + k);
        acc += fast_tanh(wq.x + uq.x) * vq.x + fast_tanh(wq.y + uq.y) * vq.y
             + fast_tanh(wq.z + uq.z) * vq.z + fast_tanh(wq.w + uq.w) * vq.w;
    }
#pragma unroll
    for (int off = 32; off > 0; off >>= 1) acc += __shfl_down(acc, off);
    if (lane == 0) e[wv] = acc + bv[0];
}

__global__ __launch_bounds__(256) void softmax_alpha(
    const float* __restrict__ e, float* __restrict__ alpha,
    float* __restrict__ alphas_out, int t)
{
    __shared__ float red[256];
    const int b = blockIdx.x, tid = threadIdx.x;
    const float v = (tid < LIMG) ? e[b * LIMG + tid] : -3.0e38f;
    red[tid] = v; __syncthreads();
    for (int s = 128; s > 0; s >>= 1) {
        if (tid < s) red[tid] = fmaxf(red[tid], red[tid + s]);
        __syncthreads();
    }
    const float mx = red[0]; __syncthreads();
    const float ex = (tid < LIMG) ? __expf(v - mx) : 0.f;
    red[tid] = ex; __syncthreads();
    for (int s = 128; s > 0; s >>= 1) {
        if (tid < s) red[tid] += red[tid + s];
        __syncthreads();
    }
    const float inv = 1.f / red[0];
    if (tid < LIMG) {
        const float a = ex * inv;
        alpha[b * LIMG + tid] = a;
        alphas_out[(size_t)b * (TSTEPS * LIMG) + t * LIMG + tid] = a;
    }
}

__global__ __launch_bounds__(128) void assemble_x(
    const float* __restrict__ img, const float* __restrict__ alpha,
    const float* __restrict__ ug, const float* __restrict__ emb,
    const int* __restrict__ captions, const float* __restrict__ h,
    float* __restrict__ x, int t, int stride)
{
    const int b = blockIdx.x, y = blockIdx.y, tid = threadIdx.x;
    if (y < 4) {
        const int tok = (t == 0) ? 10001 : captions[b * 16 + (t - 1)];
        const int j = y * 128 + tid;
        x[(size_t)b * stride + j] = emb[(size_t)tok * EMBD + j];
    } else if (y < 20) {
        __shared__ float al[LIMG];
        for (int i = tid; i < LIMG; i += 128) al[i] = alpha[b * LIMG + i];
        __syncthreads();
        const int d = (y - 4) * 128 + tid;
        const float* ib = img + (size_t)b * LIMG * DIMG + d;
        float accv = 0.f;
#pragma unroll 4
        for (int l = 0; l < LIMG; l++) accv = fmaf(al[l], ib[(size_t)l * DIMG], accv);
        const float g = ug[(size_t)b * 3072 + 1024 + d];
        x[(size_t)b * stride + EMBD + d] = g * accv;
    } else {
        const int j = (y - 20) * 128 + tid;
        x[(size_t)b * stride + 2560 + j] = h[(size_t)b * RNND + j];
    }
}

extern "C" void kernel_launch(void* const* d_in, const int* in_sizes, int n_in,
                              void* d_out, int out_size, void* d_ws, size_t ws_size,
                              hipStream_t stream)
{
    const float* img      = (const float*)d_in[0];
    const int*   captions = (const int*)d_in[1];
    const float* emb      = (const float*)d_in[2];
    const float* Wih      = (const float*)d_in[3];
    const float* Whh      = (const float*)d_in[4];
    const float* bih      = (const float*)d_in[5];
    const float* bhh      = (const float*)d_in[6];
    const float* Wh0      = (const float*)d_in[7];
    const float* bh0      = (const float*)d_in[8];
    const float* Wc0      = (const float*)d_in[9];
    const float* bc0      = (const float*)d_in[10];
    const float* Wfb      = (const float*)d_in[11];
    const float* bfb      = (const float*)d_in[12];
    const float* Wout     = (const float*)d_in[13];
    const float* bout     = (const float*)d_in[14];
    const float* WU       = (const float*)d_in[15];
    const float* bU       = (const float*)d_in[16];
    const float* WW       = (const float*)d_in[17];
    const float* bW       = (const float*)d_in[18];
    const float* Wv       = (const float*)d_in[19];
    const float* bv       = (const float*)d_in[20];

    float* preds      = (float*)d_out;
    float* alphas_out = preds + (size_t)NB * TSTEPS * VOUTD;

    const size_t NEED = 190000000;

    if (ws_size >= NEED) {
        float* w = (float*)d_ws;
        float* Ws    = w; w += (size_t)12544 * 1024;   // used as bf16 (half occupied)
        float* ug    = w; w += (size_t)64 * 3072;
        float* P     = w; w += (size_t)8 * 64 * 4096;
        float* e     = w; w += (size_t)64 * LIMG;
        float* alpha = w; w += (size_t)64 * LIMG;
        float* xh    = w; w += (size_t)64 * 3584;
        float* h     = w; w += (size_t)64 * RNND;
        float* c     = w; w += (size_t)64 * RNND;
        float* avg   = w; w += (size_t)64 * DIMG;
        float* bsum  = w; w += 4096;
        float* bug   = w; w += 3072;
        short* u = (short*)w;
        short* Hbh     = u; u += (size_t)1280 * 1024;
        short* Hbl     = u; u += (size_t)1280 * 1024;
        short* WWTh    = u; u += (size_t)1024 * 2048;
        short* WWTl    = u; u += (size_t)1024 * 2048;
        short* WugTh   = u; u += (size_t)3072 * 1024;
        short* WugTl   = u; u += (size_t)3072 * 1024;
        short* WfullTh = u; u += (size_t)4096 * 3584;
        short* WfullTl = u; u += (size_t)4096 * 3584;
        short* WoutTh  = u; u += (size_t)10112 * 1024;
        short* WoutTl  = u; u += (size_t)10112 * 1024;

        mean_img<<<dim3(NB, 8), 256, 0, stream>>>(img, avg);
        gemm64<<<dim3(16, 1, 8), 256, 0, stream>>>(avg, Wh0, nullptr, P, 1024, 2048, 256, 0, 0, 0);
        reduce_partials<<<256, 256, 0, stream>>>(P, 8, 1024, bh0, h, 1024, 1);
        gemm64<<<dim3(16, 1, 8), 256, 0, stream>>>(avg, Wc0, nullptr, P, 1024, 2048, 256, 0, 0, 0);
        reduce_partials<<<256, 256, 0, stream>>>(P, 8, 1024, bc0, c, 1024, 1);
        concat_b<<<16, 256, 0, stream>>>(bU, bfb, bih, bhh, bug, bsum);

        tsplit<<<dim3(32, 16), 256, 0, stream>>>(WW, 1024, WW, 1024, WWTh, WWTl, 1024, 2048, 2048, 0);
        tsplit<<<dim3(16, 48), 256, 0, stream>>>(WU, 1024, Wfb, 2048, WugTh, WugTl, 3072, 1024, 1024, 1024);
        tsplit<<<dim3(56, 64), 256, 0, stream>>>(Wih, 4096, Whh, 4096, WfullTh, WfullTl, 4096, 3584, 2560, 0);
        tsplit<<<dim3(16, 157), 256, 0, stream>>>(Wout, VOUTD, Wout, VOUTD, WoutTh, WoutTl, VOUTD, 1024, 1024, 0);

        // W_s = img @ WW + bW : bf16 output (halves write + 17x read traffic)
        gemm_mt<<<dim3(8, 196), 256, 0, stream>>>(img, nullptr, nullptr, WWTh, WWTl,
                                                  bW, Ws, 1024, 2048, 2048, 2048, 1024, 0, 1);

        for (int t = 0; t < TSTEPS; t++) {
            gemm_sk<<<dim3(24, 1, 8), 256, 0, stream>>>(h, WugTh, WugTl, P, 3072, 1024, 1024, 1024, 128);
            attn_e2<<<3136, 256, 0, stream>>>(P, bug, (const short*)Ws, Wv, bv, e);
            ctx_fuse2<<<dim3(NB, 5), 256, 0, stream>>>(e, P, bug, img, emb, captions, h, xh, alphas_out, t);
            gemm_sk<<<dim3(32, 1, 7), 256, 0, stream>>>(xh, WfullTh, WfullTl, P, 4096, 3584, 3584, 3584, 512);
            reduce_lstm<<<256, 256, 0, stream>>>(P, 7, bsum, h, c,
                                                 Hbh + (size_t)(t + 1) * 65536,
                                                 Hbl + (size_t)(t + 1) * 65536);
        }

        // preds: fp32 output, pmap
        gemm_mt<<<dim3(79, 17), 256, 0, stream>>>(nullptr, Hbh + 65536, Hbl + 65536,
                                                  WoutTh, WoutTl, bout, preds,
                                                  VOUTD, 1024, 1024, 1024, VOUTD, 1, 0);
        (void)ug; (void)alpha;
    } else {
        float* w = (float*)d_ws;
        float* Ws    = w; w += (size_t)12544 * 1024;
        float* ug    = w; w += (size_t)64 * 3072;
        float* P     = w; w += (size_t)12 * 64 * 4096;
        float* e     = w; w += (size_t)64 * LIMG;
        float* alpha = w; w += (size_t)64 * LIMG;
        float* x     = w; w += (size_t)64 * 2560;
        float* Hh    = w; w += (size_t)18 * 64 * RNND;
        float* c     = w; w += (size_t)64 * RNND;
        float* avg   = w; w += (size_t)64 * DIMG;
        float* bsum  = w; w += 4096;
        float* Wug   = w; w += (size_t)1024 * 3072;
        float* bug   = w; w += 3072;

        mean_img<<<dim3(NB, 8), 256, 0, stream>>>(img, avg);
        gemm64<<<dim3(16, 1, 8), 256, 0, stream>>>(avg, Wh0, nullptr, P, 1024, 2048, 256, 0, 0, 0);
        reduce_partials<<<256, 256, 0, stream>>>(P, 8, 1024, bh0, Hh, 1024, 1);
        gemm64<<<dim3(16, 1, 8), 256, 0, stream>>>(avg, Wc0, nullptr, P, 1024, 2048, 256, 0, 0, 0);
        reduce_partials<<<256, 256, 0, stream>>>(P, 8, 1024, bc0, c, 1024, 1);
        concat_b<<<16, 256, 0, stream>>>(bU, bfb, bih, bhh, bug, bsum);
        concat_w<<<12288, 256, 0, stream>>>(WU, Wfb, Wug);
        gemm_mfma3<<<dim3(8, 98), 256, 0, stream>>>(img, WW, bW, Ws,
                                                    12544, 1024, 2048, 2048, 1024, 1024, 0);
        for (int t = 0; t < TSTEPS; t++) {
            const float* hc = Hh + (size_t)t * 64 * RNND;
            float*       hn = Hh + (size_t)(t + 1) * 64 * RNND;
            gemm64<<<dim3(48, 1, 8), 256, 0, stream>>>(hc, Wug, nullptr, P, 3072, 1024, 128, 0, 0, 0);
            reduce_partials<<<768, 256, 0, stream>>>(P, 8, 3072, bug, ug, 3072, 3);
            attn_e<<<3136, 256, 0, stream>>>(Ws, ug, Wv, bv, e);
            softmax_alpha<<<NB, 256, 0, stream>>>(e, alpha, alphas_out, t);
            assemble_x<<<dim3(NB, 20), 128, 0, stream>>>(img, alpha, ug, emb, captions, hc, x, t, 2560);
            gemm64<<<dim3(64, 1, 8), 256, 0, stream>>>(x, Wih, nullptr, P, 4096, 2560, 320, 0, 0, 0);
            gemm64<<<dim3(64, 1, 4), 256, 0, stream>>>(hc, Whh, nullptr, P + (size_t)8 * 64 * 4096,
                                                       4096, 1024, 256, 0, 0, 0);
            reduce_lstm<<<256, 256, 0, stream>>>(P, 12, bsum, hn, c, nullptr, nullptr);
        }
        gemm_mfma3<<<dim3(79, 9), 256, 0, stream>>>(Hh + (size_t)64 * RNND, Wout, bout, preds,
                                                    TSTEPS * 64, VOUTD, 1024, 1024, VOUTD, VOUTD, 1);
    }
}